// Round 4
// baseline (212.207 us; speedup 1.0000x reference)
//
#include <hip/hip_runtime.h>
#include <hip/hip_bf16.h>
#include <math.h>
#include <float.h>

// Problem constants (fixed by setup_inputs)
#define BATCH 108
#define NNODE 392
#define IDIM  256
#define HEADS 4
#define ODIM  64
#define HO    256            // HEADS*ODIM
#define MROWS (BATCH*NNODE)  // 42336
#define SGH   (BATCH*HEADS*NNODE)  // 169344

typedef __attribute__((ext_vector_type(8))) short bf16x8;
typedef __attribute__((ext_vector_type(8))) unsigned short u16x8;
typedef __attribute__((ext_vector_type(4))) float f32x4;

// exact RNE f32->bf16 (known-good; do NOT replace with v_cvt_pk_bf16_f32 —
// R1 showed that instruction's rounding breaks the absmax check: 7.6e-2 vs 7.8e-3)
__device__ __forceinline__ ushort f2bf(float f) {
    unsigned u = __float_as_uint(f);
    unsigned r = (u + 0x7FFFu + ((u >> 16) & 1u)) >> 16;   // RNE
    return (ushort)r;
}
__device__ __forceinline__ float bf2f(ushort h) {
    return __uint_as_float(((unsigned)h) << 16);
}
// fast sigmoid: v_mul + v_exp + v_add + v_rcp (kept from R2: VALUBusy 31->20%)
__device__ __forceinline__ float fsigmoid(float x) {
    float e = __expf(-x);
    return __builtin_amdgcn_rcpf(1.0f + e);
}

#define MSTR 264   // LDS row stride (256 + 8 pad)

// weight fragment fetch from pre-shuffled layout
#define WFRAG(src, jn, k0t) \
    (*(const bf16x8*)((src) + ((((wg * 4 + (jn)) * 8 + (k0t)) << 9)) + lane * 8))

// ---------------------------------------------------------------------------
// Fused double-GEMM. R4: target VGPR<=64 (8 waves/SIMD tier; R3 was 80 VGPR
// -> 4 waves/SIMD, occupancy 22.6%, ~65% of cycles exposed latency).
// - jn-split weight streaming: <=24 weight VGPRs live (was 32)
// - bmlp/askv/ankv loaded per-jn in epilogues (was 16-32 regs front-loaded)
// - zbacc atomic deferred to kernel end via LDS (removes vmcnt(0) drain
//   the compiler emits before barrier 3)
__global__ __launch_bounds__(256, 8)
void fused_gemm(const float* __restrict__ x, const ushort* __restrict__ wshuf,
                const ushort* __restrict__ kshuf, const float* __restrict__ bmlp,
                float* __restrict__ zbacc, ushort* __restrict__ xp0,
                const float* __restrict__ askv, const float* __restrict__ ankv,
                float* __restrict__ s0, float* __restrict__ ng0)
{
    __shared__ __attribute__((aligned(16))) ushort AsMs[32 * MSTR]; // x bf16 / mlp bf16
    __shared__ float cs_lds[256];   // per-block mlp col sums (deferred atomic)

    const int t    = threadIdx.x;
    const int lane = t & 63;
    const int wg   = t >> 6;            // 0..3 col-group / head
    const int lr   = lane & 15, kq = lane >> 4;
    const int rb   = blockIdx.x;        // 0..12 row-block within batch
    const int b    = blockIdx.y;
    const int row0 = rb * 32;
    const long gbase = (long)b * NNODE;

    // prefetch phase-1 jn=0,1 k0t=0 weight fragments (overlaps x staging)
    bf16x8 w0 = WFRAG(wshuf, 0, 0);
    bf16x8 w1 = WFRAG(wshuf, 1, 0);

    // ---- stage 32x256 x block (fp32 -> bf16), coalesced ----
    {
        const float* xb = x + (gbase + row0) * 256;
        #pragma unroll
        for (int j = 0; j < 8; ++j) {
            int e4  = t + j * 256;
            int row = e4 >> 6;
            int col = (e4 & 63) * 4;
            float4 v = (row0 + row < NNODE)
                ? *(const float4*)(xb + (long)row * 256 + col)
                : make_float4(0.f, 0.f, 0.f, 0.f);
            *(ushort4*)&AsMs[row * MSTR + col] =
                make_ushort4(f2bf(v.x), f2bf(v.y), f2bf(v.z), f2bf(v.w));
        }
    }
    __syncthreads();                        // barrier 1

    f32x4 acc[4][2] = {};   // [jn][imL]

    // ---------------- phase 1: mlp = sigmoid(x @ W + b) ----------------
    {
        #pragma unroll
        for (int k0t = 0; k0t < 8; ++k0t) {
            bf16x8 xf0 = *(const bf16x8*)&AsMs[lr * MSTR + k0t * 32 + kq * 8];
            bf16x8 xf1 = *(const bf16x8*)&AsMs[(16 + lr) * MSTR + k0t * 32 + kq * 8];
            bf16x8 n0 = WFRAG(wshuf, 2, k0t);
            bf16x8 n1 = WFRAG(wshuf, 3, k0t);
            acc[0][0] = __builtin_amdgcn_mfma_f32_16x16x32_bf16(w0, xf0, acc[0][0], 0, 0, 0);
            acc[0][1] = __builtin_amdgcn_mfma_f32_16x16x32_bf16(w0, xf1, acc[0][1], 0, 0, 0);
            acc[1][0] = __builtin_amdgcn_mfma_f32_16x16x32_bf16(w1, xf0, acc[1][0], 0, 0, 0);
            acc[1][1] = __builtin_amdgcn_mfma_f32_16x16x32_bf16(w1, xf1, acc[1][1], 0, 0, 0);
            if (k0t < 7) {
                w0 = WFRAG(wshuf, 0, k0t + 1);
                w1 = WFRAG(wshuf, 1, k0t + 1);
            }
            acc[2][0] = __builtin_amdgcn_mfma_f32_16x16x32_bf16(n0, xf0, acc[2][0], 0, 0, 0);
            acc[2][1] = __builtin_amdgcn_mfma_f32_16x16x32_bf16(n0, xf1, acc[2][1], 0, 0, 0);
            acc[3][0] = __builtin_amdgcn_mfma_f32_16x16x32_bf16(n1, xf0, acc[3][0], 0, 0, 0);
            acc[3][1] = __builtin_amdgcn_mfma_f32_16x16x32_bf16(n1, xf1, acc[3][1], 0, 0, 0);
        }
    }

    // prefetch phase-2 jn=0,1 k0t=0 fragments (drained at barrier 2, ready for GEMM2)
    bf16x8 k0f = WFRAG(kshuf, 0, 0);
    bf16x8 k1f = WFRAG(kshuf, 1, 0);

    __syncthreads();                        // barrier 2

    // ---- epilogue 1: sigmoid -> Ms (aliases x); col sums -> cs_lds ----
    {
        float cs[4][4] = {};
        #pragma unroll
        for (int imL = 0; imL < 2; ++imL) {
            const int r_ = 16 * imL + lr;
            const bool ok = row0 + r_ < NNODE;
            #pragma unroll
            for (int jn = 0; jn < 4; ++jn) {
                const float4 bij = *(const float4*)(bmlp + 64 * wg + 16 * jn + 4 * kq);
                float v[4];
                v[0] = fsigmoid(acc[jn][imL][0] + bij.x);
                v[1] = fsigmoid(acc[jn][imL][1] + bij.y);
                v[2] = fsigmoid(acc[jn][imL][2] + bij.z);
                v[3] = fsigmoid(acc[jn][imL][3] + bij.w);
                *(ushort4*)&AsMs[r_ * MSTR + 64 * wg + 16 * jn + 4 * kq] =
                    make_ushort4(f2bf(v[0]), f2bf(v[1]), f2bf(v[2]), f2bf(v[3]));
                if (ok) {
                    cs[jn][0] += v[0]; cs[jn][1] += v[1];
                    cs[jn][2] += v[2]; cs[jn][3] += v[3];
                }
            }
        }
        #pragma unroll
        for (int jn = 0; jn < 4; ++jn)
            #pragma unroll
            for (int r = 0; r < 4; ++r) {
                float v = cs[jn][r];
                v += __shfl_xor(v, 1, 64);
                v += __shfl_xor(v, 2, 64);
                v += __shfl_xor(v, 4, 64);
                v += __shfl_xor(v, 8, 64);
                if (lr == 0)
                    cs_lds[64 * wg + 16 * jn + 4 * kq + r] = v;
            }
    }
    __syncthreads();                        // barrier 3

    // ---------------- phase 2: xp0 = 0.2 * (Ms @ K^T) ----------------
    #pragma unroll
    for (int jn = 0; jn < 4; ++jn)
        #pragma unroll
        for (int imL = 0; imL < 2; ++imL)
            acc[jn][imL] = f32x4{0.f, 0.f, 0.f, 0.f};

    {
        #pragma unroll
        for (int k0t = 0; k0t < 8; ++k0t) {
            bf16x8 xf0 = *(const bf16x8*)&AsMs[lr * MSTR + k0t * 32 + kq * 8];
            bf16x8 xf1 = *(const bf16x8*)&AsMs[(16 + lr) * MSTR + k0t * 32 + kq * 8];
            bf16x8 n0 = WFRAG(kshuf, 2, k0t);
            bf16x8 n1 = WFRAG(kshuf, 3, k0t);
            acc[0][0] = __builtin_amdgcn_mfma_f32_16x16x32_bf16(k0f, xf0, acc[0][0], 0, 0, 0);
            acc[0][1] = __builtin_amdgcn_mfma_f32_16x16x32_bf16(k0f, xf1, acc[0][1], 0, 0, 0);
            acc[1][0] = __builtin_amdgcn_mfma_f32_16x16x32_bf16(k1f, xf0, acc[1][0], 0, 0, 0);
            acc[1][1] = __builtin_amdgcn_mfma_f32_16x16x32_bf16(k1f, xf1, acc[1][1], 0, 0, 0);
            if (k0t < 7) {
                k0f = WFRAG(kshuf, 0, k0t + 1);
                k1f = WFRAG(kshuf, 1, k0t + 1);
            }
            acc[2][0] = __builtin_amdgcn_mfma_f32_16x16x32_bf16(n0, xf0, acc[2][0], 0, 0, 0);
            acc[2][1] = __builtin_amdgcn_mfma_f32_16x16x32_bf16(n0, xf1, acc[2][1], 0, 0, 0);
            acc[3][0] = __builtin_amdgcn_mfma_f32_16x16x32_bf16(n1, xf0, acc[3][0], 0, 0, 0);
            acc[3][1] = __builtin_amdgcn_mfma_f32_16x16x32_bf16(n1, xf1, acc[3][1], 0, 0, 0);
        }
    }

    // ---- epilogue 2: xp0 stores + fused s0/ng0 projections (jn-outer) ----
    {
        const int h = wg;
        float ps[2] = {0.f, 0.f}, pn[2] = {0.f, 0.f};
        #pragma unroll
        for (int jn = 0; jn < 4; ++jn) {
            float ak[4], an[4];
            #pragma unroll
            for (int r = 0; r < 4; ++r) {
                int o = 16 * jn + 4 * kq + r;
                ak[r] = askv[o * HEADS + h];
                an[r] = ankv[o * HEADS + h];
            }
            #pragma unroll
            for (int imL = 0; imL < 2; ++imL) {
                const int lrow = row0 + 16 * imL + lr;
                if (lrow < NNODE) {
                    float v0 = 0.2f * acc[jn][imL][0];
                    float v1 = 0.2f * acc[jn][imL][1];
                    float v2 = 0.2f * acc[jn][imL][2];
                    float v3 = 0.2f * acc[jn][imL][3];
                    *(ushort4*)(xp0 + (gbase + lrow) * 256 + 64 * h + 16 * jn + 4 * kq) =
                        make_ushort4(f2bf(v0), f2bf(v1), f2bf(v2), f2bf(v3));
                    ps[imL] += v0 * ak[0] + v1 * ak[1] + v2 * ak[2] + v3 * ak[3];
                    pn[imL] += v0 * an[0] + v1 * an[1] + v2 * an[2] + v3 * an[3];
                }
            }
        }
        #pragma unroll
        for (int imL = 0; imL < 2; ++imL) {
            float p1 = ps[imL], p2 = pn[imL];
            p1 += __shfl_xor(p1, 16, 64);
            p1 += __shfl_xor(p1, 32, 64);
            p2 += __shfl_xor(p2, 16, 64);
            p2 += __shfl_xor(p2, 32, 64);
            const int lrow = row0 + 16 * imL + lr;
            if (lrow < NNODE && kq == 0) {
                long si = ((long)b * HEADS + h) * NNODE + lrow;
                s0[si]  = p1;
                ng0[si] = p2;
            }
        }
    }

    // deferred zbacc accumulation (after all barriers; cs_lds valid since
    // barrier 3 and untouched afterwards)
    atomicAdd(&zbacc[b * 256 + t], cs_lds[t]);
}

// ---------------------------------------------------------------------------
// Weight transpose + bf16 + MFMA-fragment shuffle; also zeroes zbacc
// (blocks 0..107 cover BATCH*IDIM = 27648 floats) -> saves a memset dispatch.
__global__ __launch_bounds__(256)
void wcvt(const float* __restrict__ w_mlp, const float* __restrict__ kern,
          ushort* __restrict__ wshuf, ushort* __restrict__ kshuf,
          float* __restrict__ zbacc)
{
    if (blockIdx.x < BATCH)
        zbacc[blockIdx.x * 256 + threadIdx.x] = 0.0f;
    long idx = (long)(blockIdx.x & 255) * 256 + threadIdx.x;   // 0..65535
    const float* src = (blockIdx.x < 256) ? w_mlp : kern;
    ushort* dst = (blockIdx.x < 256) ? wshuf : kshuf;
    int e    = idx & 7;
    int lane = (int)(idx >> 3) & 63;
    int k0t  = (int)(idx >> 9) & 7;
    int jn   = (int)(idx >> 12) & 3;
    int g    = (int)(idx >> 14);
    int n = 64 * g + 16 * jn + (lane & 15);
    int k = 32 * k0t + (lane >> 4) * 8 + e;
    dst[idx] = f2bf(src[(long)k * 256 + n]);
}

// ---------------------------------------------------------------------------
// zbK[b,c] = (0.8/N * zbacc[b]) @ kernel; also per-(b,h) projection consts.
// 1024 threads: k split into 4 chunks of 64.
__global__ __launch_bounds__(1024)
void zbk_k(const float* __restrict__ zbacc, const float* __restrict__ kern,
           const float* __restrict__ askv, const float* __restrict__ ankv,
           float* __restrict__ zbK, float* __restrict__ sb,
           float* __restrict__ ngb)
{
    __shared__ float zrow[IDIM];
    __shared__ float part[4][IDIM];
    const int b = blockIdx.x, t = threadIdx.x;
    if (t < IDIM) zrow[t] = zbacc[b * 256 + t] * (0.8f / (float)NNODE);
    __syncthreads();
    const int c = t & 255, kc = t >> 8;
    float acc = 0.0f;
    #pragma unroll
    for (int kk = 0; kk < 64; ++kk) {
        int k = kc * 64 + kk;
        acc = fmaf(zrow[k], kern[(long)k * HO + c], acc);
    }
    part[kc][c] = acc;
    __syncthreads();
    if (t < IDIM) {
        float a = part[0][t] + part[1][t] + part[2][t] + part[3][t];
        zbK[b * 256 + t] = a;
        int h = t >> 6, o = t & 63;
        float ps = a * askv[o * HEADS + h];
        float pn = a * ankv[o * HEADS + h];
        #pragma unroll
        for (int off = 32; off; off >>= 1) {
            ps += __shfl_down(ps, off, 64);
            pn += __shfl_down(pn, off, 64);
        }
        if (o == 0) {
            sb[b * HEADS + h]  = ps;
            ngb[b * HEADS + h] = pn;
        }
    }
}

// ---------------------------------------------------------------------------
// attn_stats: per (b,h): keys = ng0 + ngb[bh], bitonic sort, denominator
// scans, per-row threshold; perm+threshold packed. 512 threads.
__global__ __launch_bounds__(512)
void attn_stats(const float* __restrict__ s0, const float* __restrict__ ng0,
                const float* __restrict__ sb, const float* __restrict__ ngb,
                uint* __restrict__ ptG, float2* __restrict__ w12G,
                float2* __restrict__ g12G)
{
    __shared__ float key[512];
    __shared__ int   perm[512];
    __shared__ float w1[NNODE], w2[NNODE];
    __shared__ float D1[NNODE + 1], D2[NNODE + 1];
    __shared__ float CT1[16], CT2[16];

    const int t = threadIdx.x;
    const int bh = blockIdx.x;
    const long base = (long)bh * NNODE;
    const float ngc = ngb[bh], sc = sb[bh];

    key[t]  = (t < NNODE) ? (ng0[base + t] + ngc) : FLT_MAX;
    perm[t] = t;
    __syncthreads();

    for (int k = 2; k <= 512; k <<= 1) {
        for (int j = k >> 1; j > 0; j >>= 1) {
            int l = t ^ j;
            if (l > t) {
                bool dir = ((t & k) == 0);
                float ki = key[t], kl = key[l];
                if ((ki > kl) == dir) {
                    key[t] = kl; key[l] = ki;
                    int pi = perm[t]; perm[t] = perm[l]; perm[l] = pi;
                }
            }
            __syncthreads();
        }
    }

    if (t < NNODE) {
        w1[t] = __expf(key[t]);
        w2[t] = __expf(0.2f * key[t]);
    }
    __syncthreads();

    if (t < 16) {
        float a1 = 0.0f;
        for (int jj = 24; jj >= 0; --jj) {
            int j = t * 25 + jj;
            if (j < NNODE) { a1 += w1[j]; D1[j] = a1; }
        }
        CT1[t] = a1;
    } else if (t < 32) {
        int c = t - 16;
        float a2 = 0.0f;
        for (int jj = 0; jj < 25; ++jj) {
            int j = c * 25 + jj;
            if (j < NNODE) { D2[j] = a2; a2 += w2[j]; }
        }
        CT2[c] = a2;
    }
    __syncthreads();
    if (t < 16) {
        float off = 0.0f;
        for (int cc = t + 1; cc < 16; ++cc) off += CT1[cc];
        for (int jj = 0; jj < 25; ++jj) {
            int j = t * 25 + jj;
            if (j < NNODE) D1[j] += off;
        }
    } else if (t < 32) {
        int c = t - 16;
        float off = 0.0f;
        for (int cc = 0; cc < c; ++cc) off += CT2[cc];
        for (int jj = 0; jj < 25; ++jj) {
            int j = c * 25 + jj;
            if (j < NNODE) D2[j] += off;
        }
    } else if (t == 32) {
        D1[NNODE] = 0.0f;
    } else if (t == 33) {
        float tot = 0.0f;
        for (int cc = 0; cc < 16; ++cc) tot += CT2[cc];
        D2[NNODE] = tot;
    }
    __syncthreads();

    if (t < NNODE) {
        float sn = s0[base + t] + sc;
        float negs = -sn;
        int lo = 0, hi = NNODE;
        while (lo < hi) {
            int mid = (lo + hi) >> 1;
            if (key[mid] < negs) lo = mid + 1; else hi = mid;
        }
        float e1 = __expf(sn), e2 = __expf(0.2f * sn);
        float inv = __builtin_amdgcn_rcpf(e1 * D1[lo] + e2 * D2[lo]);
        ptG[base + t]  = (uint)perm[t] | ((uint)lo << 16);
        g12G[base + t] = make_float2(e1 * inv, e2 * inv);
        w12G[base + t] = make_float2(w1[t], w2[t]);
    }
}

// ---------------------------------------------------------------------------
// attn_scan: block = (og, bh); 16 o-cols, 1024 threads = 64 chunks x 16.
// 32 B/row gather, column-major LDS. Cross-chunk offsets via 6-step
// Hillis-Steele tree scans over CT (replaces 63-deep serial LDS loops).
// out = elu(g1*S1[t] + g2*S2[t] + zbK[b][col] + bias).
#define CHN 7    // chunk depth: 64*7 = 448 >= 392
#define NP  (NNODE + 1)
__global__ __launch_bounds__(1024)
void attn_scan(const ushort* __restrict__ xp, const uint* __restrict__ ptG,
               const float2* __restrict__ w12G, const float2* __restrict__ g12G,
               const float* __restrict__ zbK, const float* __restrict__ bias,
               float* __restrict__ out)
{
    __shared__ float  Vs[16 * NP];
    __shared__ float  S1[16 * NP];
    __shared__ float  w1s[NNODE], w2s[NNODE], g1s[NNODE], g2s[NNODE];
    __shared__ ushort perms[NNODE], tls[NNODE];
    __shared__ float  CT[64][17], CT2[64][17];
    __shared__ float  biasl[16];

    const int t  = threadIdx.x;
    const int og = blockIdx.x;          // 0..3
    const int bh = blockIdx.y;          // 0..431
    const int b  = bh >> 2, h = bh & 3;
    const long base = (long)bh * NNODE;
    const int c0 = h * 64 + og * 16;

    if (t < NNODE) {
        uint pt = ptG[base + t];
        perms[t] = (ushort)(pt & 0xFFFFu);
        tls[t]   = (ushort)(pt >> 16);
        float2 w = w12G[base + t];
        w1s[t] = w.x; w2s[t] = w.y;
    } else if (t >= 512 && t < 512 + NNODE) {
        int i = t - 512;
        float2 g = g12G[base + i];
        g1s[i] = g.x; g2s[i] = g.y;
    }
    if (t < 16) biasl[t] = bias[c0 + t] + zbK[b * 256 + c0 + t];
    __syncthreads();

    // gather: 2 x uint4 (8 bf16 each) per sorted row; column-major scatter
    if (t < NNODE * 2) {
        int j = t >> 1, q = (t & 1) * 8;
        int m = perms[j];
        u16x8 raw = *(const u16x8*)(xp + ((long)b * NNODE + m) * HO + c0 + q);
        #pragma unroll
        for (int oo = 0; oo < 8; ++oo) Vs[(q + oo) * NP + j] = bf2f(raw[oo]);
    }
    __syncthreads();

    const int c = t >> 4, o = t & 15;   // 64 chunks x 16 cols

    // S1: w1-weighted suffix sums within chunk
    {
        float acc = 0.0f;
        #pragma unroll
        for (int jj = CHN - 1; jj >= 0; --jj) {
            int j = c * CHN + jj;
            if (j < NNODE) {
                acc = fmaf(w1s[j], Vs[o * NP + j], acc);
                S1[o * NP + j] = acc;
            }
        }
        CT[c][o] = acc;
    }
    __syncthreads();
    // tree-scan CT into inclusive SUFFIX sums over c (6 steps)
    #pragma unroll
    for (int s = 1; s < 64; s <<= 1) {
        float add = (c + s < 64) ? CT[c + s][o] : 0.0f;
        __syncthreads();
        CT[c][o] += add;
        __syncthreads();
    }
    {
        float off = (c < 63) ? CT[c + 1][o] : 0.0f;
        #pragma unroll
        for (int jj = 0; jj < CHN; ++jj) {
            int j = c * CHN + jj;
            if (j < NNODE) S1[o * NP + j] += off;
        }
        if (c == 0) S1[o * NP + NNODE] = 0.0f;
    }
    // S2: w2-weighted exclusive prefix within chunk, in place over Vs
    {
        float acc = 0.0f;
        #pragma unroll
        for (int jj = 0; jj < CHN; ++jj) {
            int j = c * CHN + jj;
            if (j < NNODE) {
                float tmp = Vs[o * NP + j];
                Vs[o * NP + j] = acc;
                acc = fmaf(w2s[j], tmp, acc);
            }
        }
        CT2[c][o] = acc;
    }
    __syncthreads();
    // tree-scan CT2 into inclusive PREFIX sums over c (6 steps)
    #pragma unroll
    for (int s = 1; s < 64; s <<= 1) {
        float add = (c >= s) ? CT2[c - s][o] : 0.0f;
        __syncthreads();
        CT2[c][o] += add;
        __syncthreads();
    }
    {
        float off = (c > 0) ? CT2[c - 1][o] : 0.0f;
        #pragma unroll
        for (int jj = 0; jj < CHN; ++jj) {
            int j = c * CHN + jj;
            if (j < NNODE) Vs[o * NP + j] += off;
        }
        if (c == 63) Vs[o * NP + NNODE] = CT2[63][o];
    }
    __syncthreads();

    // emit: float4 per (row, col-quad)
    for (int idx = t; idx < NNODE * 4; idx += 1024) {
        int n = idx >> 2, q = (idx & 3) * 4;
        int tt = tls[n];
        float g1 = g1s[n], g2 = g2s[n];
        float r[4];
        #pragma unroll
        for (int rr = 0; rr < 4; ++rr) {
            int oo = q + rr;
            float v = g1 * S1[oo * NP + tt] + g2 * Vs[oo * NP + tt] + biasl[oo];
            r[rr] = (v > 0.0f) ? v : (__expf(v) - 1.0f);
        }
        *(float4*)(out + ((long)b * NNODE + n) * HO + c0 + q) =
            make_float4(r[0], r[1], r[2], r[3]);
    }
}

extern "C" void kernel_launch(void* const* d_in, const int* in_sizes, int n_in,
                              void* d_out, int out_size, void* d_ws, size_t ws_size,
                              hipStream_t stream) {
    const float* x     = (const float*)d_in[0];   // [108,392,256]
    const float* w_mlp = (const float*)d_in[2];   // [256,256]
    const float* b_mlp = (const float*)d_in[3];   // [256]
    const float* kern  = (const float*)d_in[4];   // [256,4,64] == [256,256]
    const float* ask   = (const float*)d_in[5];   // [64,4,1]
    const float* ank   = (const float*)d_in[6];   // [64,4,1]
    const float* bias  = (const float*)d_in[7];   // [256]
    float* out = (float*)d_out;

    const long TENS = (long)MROWS * IDIM;         // 10,838,016
    float*  s0    = (float*)d_ws;                 // [B,H,N]
    float*  ng0   = s0 + SGH;
    float*  zbacc = ng0 + SGH;                    // [B,256] atomically built
    float*  zbK   = zbacc + (long)BATCH * IDIM;   // [B,256]
    float*  sb    = zbK + (long)BATCH * HO;       // [B,H]
    float*  ngb   = sb + BATCH * HEADS;           // [B,H]
    float2* w12G  = (float2*)(ngb + BATCH * HEADS);
    float2* g12G  = w12G + SGH;
    uint*   ptG   = (uint*)(g12G + SGH);
    ushort* xp_bf = (ushort*)(ptG + SGH);         // [B,N,H*O] bf16 (xp0)
    ushort* wshuf = xp_bf + TENS;                 // [65536] frag-order w_mlp
    ushort* kshuf = wshuf + 65536;                // [65536] frag-order kernel

    dim3 blk(256);

    // 0) weight shuffle + zbacc zeroing (fused)
    wcvt<<<dim3(512), blk, 0, stream>>>(w_mlp, kern, wshuf, kshuf, zbacc);

    // 1) fused: mlp(sigmoid, LDS-only) -> col-sums -> xp0 + s0/ng0
    fused_gemm<<<dim3(13, BATCH), dim3(256), 0, stream>>>(
        x, wshuf, kshuf, b_mlp, zbacc, xp_bf, ask, ank, s0, ng0);

    // 2) zbK = (0.8*mean mlp) @ kernel + per-(b,h) projection constants
    zbk_k<<<dim3(BATCH), dim3(1024), 0, stream>>>(zbacc, kern, ask, ank, zbK, sb, ngb);

    // 3) attention stats: const-shifted sort + denominators + thresholds
    attn_stats<<<dim3(BATCH * HEADS), dim3(512), 0, stream>>>(
        s0, ng0, sb, ngb, ptG, w12G, g12G);

    // 4) attention scan: tree-scanned prefix/suffix sums + emit
    attn_scan<<<dim3(4, BATCH * HEADS), dim3(1024), 0, stream>>>(
        xp_bf, ptG, w12G, g12G, zbK, bias, out);
}

// Round 5
// 193.882 us; speedup vs baseline: 1.0945x; 1.0945x over previous
//
#include <hip/hip_runtime.h>
#include <hip/hip_bf16.h>
#include <math.h>
#include <float.h>

// Problem constants (fixed by setup_inputs)
#define BATCH 108
#define NNODE 392
#define IDIM  256
#define HEADS 4
#define ODIM  64
#define HO    256            // HEADS*ODIM
#define MROWS (BATCH*NNODE)  // 42336
#define SGH   (BATCH*HEADS*NNODE)  // 169344

typedef __attribute__((ext_vector_type(8))) short bf16x8;
typedef __attribute__((ext_vector_type(8))) unsigned short u16x8;
typedef __attribute__((ext_vector_type(4))) float f32x4;

// exact RNE f32->bf16 (known-good; do NOT replace with v_cvt_pk_bf16_f32 —
// R1 showed that instruction's rounding breaks the absmax check: 7.6e-2 vs 7.8e-3)
__device__ __forceinline__ ushort f2bf(float f) {
    unsigned u = __float_as_uint(f);
    unsigned r = (u + 0x7FFFu + ((u >> 16) & 1u)) >> 16;   // RNE
    return (ushort)r;
}
__device__ __forceinline__ float bf2f(ushort h) {
    return __uint_as_float(((unsigned)h) << 16);
}
// fast sigmoid: v_mul + v_exp + v_add + v_rcp (kept from R2: VALUBusy 31->20%)
__device__ __forceinline__ float fsigmoid(float x) {
    float e = __expf(-x);
    return __builtin_amdgcn_rcpf(1.0f + e);
}

#define MSTR 264   // LDS row stride (256 + 8 pad)

// ---------------------------------------------------------------------------
// Fused double-GEMM — R3 structure (known-good: 80 VGPR, no spill, 43 µs).
// R4 lesson: do NOT force __launch_bounds__ min-waves — 8-wave tier caps VGPR
// at 32 and spills (+64 MB scratch traffic, 43->58 µs). Only R4 piece kept:
// zbacc atomic deferred to kernel end via LDS (removes the vmcnt(0) drain the
// compiler emits before barrier 3).
__global__ __launch_bounds__(256)
void fused_gemm(const float* __restrict__ x, const ushort* __restrict__ wshuf,
                const ushort* __restrict__ kshuf, const float* __restrict__ bmlp,
                float* __restrict__ zbacc, ushort* __restrict__ xp0,
                const float* __restrict__ askv, const float* __restrict__ ankv,
                float* __restrict__ s0, float* __restrict__ ng0)
{
    __shared__ __attribute__((aligned(16))) ushort AsMs[32 * MSTR]; // x bf16 / mlp bf16
    __shared__ float cs_lds[256];   // per-block mlp col sums (deferred atomic)

    const int t    = threadIdx.x;
    const int lane = t & 63;
    const int wg   = t >> 6;            // 0..3 col-group / head
    const int lr   = lane & 15, kq = lane >> 4;
    const int rb   = blockIdx.x;        // 0..12 row-block within batch
    const int b    = blockIdx.y;
    const int row0 = rb * 32;
    const long gbase = (long)b * NNODE;

    // prefetch phase-1 first weight fragments (no LDS dep; overlaps x staging)
    bf16x8 wfn[4];
    #pragma unroll
    for (int jn = 0; jn < 4; ++jn)
        wfn[jn] = *(const bf16x8*)
            (wshuf + (((wg * 4 + jn) * 8 + 0) << 9) + lane * 8);

    // ---- stage 32x256 x block (fp32 -> bf16), coalesced ----
    {
        const float* xb = x + (gbase + row0) * 256;
        #pragma unroll
        for (int j = 0; j < 8; ++j) {
            int e4  = t + j * 256;
            int row = e4 >> 6;
            int col = (e4 & 63) * 4;
            float4 v = (row0 + row < NNODE)
                ? *(const float4*)(xb + (long)row * 256 + col)
                : make_float4(0.f, 0.f, 0.f, 0.f);
            *(ushort4*)&AsMs[row * MSTR + col] =
                make_ushort4(f2bf(v.x), f2bf(v.y), f2bf(v.z), f2bf(v.w));
        }
    }
    __syncthreads();                        // barrier 1

    f32x4 acc[4][2] = {};   // [jn][imL]

    // ---------------- phase 1: mlp = sigmoid(x @ W + b) ----------------
    {
        #pragma unroll
        for (int k0t = 0; k0t < 8; ++k0t) {
            bf16x8 wfc[4];
            #pragma unroll
            for (int jn = 0; jn < 4; ++jn) wfc[jn] = wfn[jn];
            if (k0t < 7) {
                #pragma unroll
                for (int jn = 0; jn < 4; ++jn)
                    wfn[jn] = *(const bf16x8*)
                        (wshuf + (((wg * 4 + jn) * 8 + k0t + 1) << 9) + lane * 8);
            }
            bf16x8 xf[2];
            #pragma unroll
            for (int imL = 0; imL < 2; ++imL)
                xf[imL] = *(const bf16x8*)
                    &AsMs[(16 * imL + lr) * MSTR + k0t * 32 + kq * 8];
            #pragma unroll
            for (int jn = 0; jn < 4; ++jn)
                #pragma unroll
                for (int imL = 0; imL < 2; ++imL)
                    acc[jn][imL] = __builtin_amdgcn_mfma_f32_16x16x32_bf16(
                        wfc[jn], xf[imL], acc[jn][imL], 0, 0, 0);
        }
    }

    // prefetch phase-2 first weight fragments (overlaps epilogue 1)
    bf16x8 kfn[4];
    #pragma unroll
    for (int jn = 0; jn < 4; ++jn)
        kfn[jn] = *(const bf16x8*)
            (kshuf + (((wg * 4 + jn) * 8 + 0) << 9) + lane * 8);

    __syncthreads();                        // barrier 2

    // ---- epilogue 1: sigmoid -> Ms (aliases x); col sums -> cs_lds ----
    {
        float4 bi[4];
        #pragma unroll
        for (int jn = 0; jn < 4; ++jn)
            bi[jn] = *(const float4*)(bmlp + 64 * wg + 16 * jn + 4 * kq);
        float cs[4][4] = {};
        #pragma unroll
        for (int imL = 0; imL < 2; ++imL) {
            const int r_ = 16 * imL + lr;
            const bool ok = row0 + r_ < NNODE;
            #pragma unroll
            for (int jn = 0; jn < 4; ++jn) {
                float v[4];
                v[0] = fsigmoid(acc[jn][imL][0] + bi[jn].x);
                v[1] = fsigmoid(acc[jn][imL][1] + bi[jn].y);
                v[2] = fsigmoid(acc[jn][imL][2] + bi[jn].z);
                v[3] = fsigmoid(acc[jn][imL][3] + bi[jn].w);
                *(ushort4*)&AsMs[r_ * MSTR + 64 * wg + 16 * jn + 4 * kq] =
                    make_ushort4(f2bf(v[0]), f2bf(v[1]), f2bf(v[2]), f2bf(v[3]));
                if (ok) {
                    cs[jn][0] += v[0]; cs[jn][1] += v[1];
                    cs[jn][2] += v[2]; cs[jn][3] += v[3];
                }
            }
        }
        #pragma unroll
        for (int jn = 0; jn < 4; ++jn)
            #pragma unroll
            for (int r = 0; r < 4; ++r) {
                float v = cs[jn][r];
                v += __shfl_xor(v, 1, 64);
                v += __shfl_xor(v, 2, 64);
                v += __shfl_xor(v, 4, 64);
                v += __shfl_xor(v, 8, 64);
                if (lr == 0)
                    cs_lds[64 * wg + 16 * jn + 4 * kq + r] = v;
            }
    }
    __syncthreads();                        // barrier 3

    // ---------------- phase 2: xp0 = 0.2 * (Ms @ K^T) ----------------
    #pragma unroll
    for (int jn = 0; jn < 4; ++jn)
        #pragma unroll
        for (int imL = 0; imL < 2; ++imL)
            acc[jn][imL] = f32x4{0.f, 0.f, 0.f, 0.f};

    {
        #pragma unroll
        for (int k0t = 0; k0t < 8; ++k0t) {
            bf16x8 wfc[4];
            #pragma unroll
            for (int jn = 0; jn < 4; ++jn) wfc[jn] = kfn[jn];
            if (k0t < 7) {
                #pragma unroll
                for (int jn = 0; jn < 4; ++jn)
                    kfn[jn] = *(const bf16x8*)
                        (kshuf + (((wg * 4 + jn) * 8 + k0t + 1) << 9) + lane * 8);
            }
            bf16x8 xf[2];
            #pragma unroll
            for (int imL = 0; imL < 2; ++imL)
                xf[imL] = *(const bf16x8*)
                    &AsMs[(16 * imL + lr) * MSTR + k0t * 32 + kq * 8];
            #pragma unroll
            for (int jn = 0; jn < 4; ++jn)
                #pragma unroll
                for (int imL = 0; imL < 2; ++imL)
                    acc[jn][imL] = __builtin_amdgcn_mfma_f32_16x16x32_bf16(
                        wfc[jn], xf[imL], acc[jn][imL], 0, 0, 0);
        }
    }

    // ---- epilogue 2: xp0 stores + fused s0/ng0 projections ----
    {
        const int h = wg;
        float askr[4][4], ankr[4][4];
        #pragma unroll
        for (int jn = 0; jn < 4; ++jn)
            #pragma unroll
            for (int r = 0; r < 4; ++r) {
                int o = 16 * jn + 4 * kq + r;
                askr[jn][r] = askv[o * HEADS + h];
                ankr[jn][r] = ankv[o * HEADS + h];
            }
        #pragma unroll
        for (int imL = 0; imL < 2; ++imL) {
            const int r_ = 16 * imL + lr;
            const int lrow = row0 + r_;
            const bool ok = lrow < NNODE;
            float ps = 0.0f, pn = 0.0f;
            if (ok) {
                ushort* dst = xp0 + (gbase + lrow) * 256 + 64 * h + 4 * kq;
                #pragma unroll
                for (int jn = 0; jn < 4; ++jn) {
                    float v0 = 0.2f * acc[jn][imL][0];
                    float v1 = 0.2f * acc[jn][imL][1];
                    float v2 = 0.2f * acc[jn][imL][2];
                    float v3 = 0.2f * acc[jn][imL][3];
                    *(ushort4*)(dst + 16 * jn) =
                        make_ushort4(f2bf(v0), f2bf(v1), f2bf(v2), f2bf(v3));
                    ps += v0 * askr[jn][0] + v1 * askr[jn][1] +
                          v2 * askr[jn][2] + v3 * askr[jn][3];
                    pn += v0 * ankr[jn][0] + v1 * ankr[jn][1] +
                          v2 * ankr[jn][2] + v3 * ankr[jn][3];
                }
            }
            ps += __shfl_xor(ps, 16, 64);
            ps += __shfl_xor(ps, 32, 64);
            pn += __shfl_xor(pn, 16, 64);
            pn += __shfl_xor(pn, 32, 64);
            if (ok && kq == 0) {
                long si = ((long)b * HEADS + h) * NNODE + lrow;
                s0[si]  = ps;
                ng0[si] = pn;
            }
        }
    }

    // deferred zbacc accumulation (cs_lds complete since barrier 3 and
    // untouched afterwards; no barrier needed here)
    atomicAdd(&zbacc[b * 256 + t], cs_lds[t]);
}

// ---------------------------------------------------------------------------
// Weight transpose + bf16 + MFMA-fragment shuffle; also zeroes zbacc
// (blocks 0..107 cover BATCH*IDIM = 27648 floats) -> saves a memset dispatch.
__global__ __launch_bounds__(256)
void wcvt(const float* __restrict__ w_mlp, const float* __restrict__ kern,
          ushort* __restrict__ wshuf, ushort* __restrict__ kshuf,
          float* __restrict__ zbacc)
{
    if (blockIdx.x < BATCH)
        zbacc[blockIdx.x * 256 + threadIdx.x] = 0.0f;
    long idx = (long)(blockIdx.x & 255) * 256 + threadIdx.x;   // 0..65535
    const float* src = (blockIdx.x < 256) ? w_mlp : kern;
    ushort* dst = (blockIdx.x < 256) ? wshuf : kshuf;
    int e    = idx & 7;
    int lane = (int)(idx >> 3) & 63;
    int k0t  = (int)(idx >> 9) & 7;
    int jn   = (int)(idx >> 12) & 3;
    int g    = (int)(idx >> 14);
    int n = 64 * g + 16 * jn + (lane & 15);
    int k = 32 * k0t + (lane >> 4) * 8 + e;
    dst[idx] = f2bf(src[(long)k * 256 + n]);
}

// ---------------------------------------------------------------------------
// zbK[b,c] = (0.8/N * zbacc[b]) @ kernel; also per-(b,h) projection consts.
// 1024 threads: k split into 4 chunks of 64.
__global__ __launch_bounds__(1024)
void zbk_k(const float* __restrict__ zbacc, const float* __restrict__ kern,
           const float* __restrict__ askv, const float* __restrict__ ankv,
           float* __restrict__ zbK, float* __restrict__ sb,
           float* __restrict__ ngb)
{
    __shared__ float zrow[IDIM];
    __shared__ float part[4][IDIM];
    const int b = blockIdx.x, t = threadIdx.x;
    if (t < IDIM) zrow[t] = zbacc[b * 256 + t] * (0.8f / (float)NNODE);
    __syncthreads();
    const int c = t & 255, kc = t >> 8;
    float acc = 0.0f;
    #pragma unroll
    for (int kk = 0; kk < 64; ++kk) {
        int k = kc * 64 + kk;
        acc = fmaf(zrow[k], kern[(long)k * HO + c], acc);
    }
    part[kc][c] = acc;
    __syncthreads();
    if (t < IDIM) {
        float a = part[0][t] + part[1][t] + part[2][t] + part[3][t];
        zbK[b * 256 + t] = a;
        int h = t >> 6, o = t & 63;
        float ps = a * askv[o * HEADS + h];
        float pn = a * ankv[o * HEADS + h];
        #pragma unroll
        for (int off = 32; off; off >>= 1) {
            ps += __shfl_down(ps, off, 64);
            pn += __shfl_down(pn, off, 64);
        }
        if (o == 0) {
            sb[b * HEADS + h]  = ps;
            ngb[b * HEADS + h] = pn;
        }
    }
}

// ---------------------------------------------------------------------------
// attn_stats: per (b,h): keys = ng0 + ngb[bh]. R5: register-resident bitonic
// sort — 39 of 45 stages have partner distance j<64 (within-wave) and use
// __shfl_xor with NO barrier; only the 6 j>=64 stages go through LDS.
// Barriers in sort: 45 -> 12. Result is bit-identical to the LDS version
// (same compare & tie semantics). 512 threads, 1 elem/thread.
__global__ __launch_bounds__(512)
void attn_stats(const float* __restrict__ s0, const float* __restrict__ ng0,
                const float* __restrict__ sb, const float* __restrict__ ngb,
                uint* __restrict__ ptG, float2* __restrict__ w12G,
                float2* __restrict__ g12G)
{
    __shared__ float key[512];
    __shared__ int   perm[512];
    __shared__ float w1[NNODE], w2[NNODE];
    __shared__ float D1[NNODE + 1], D2[NNODE + 1];
    __shared__ float CT1[16], CT2[16];

    const int t = threadIdx.x;
    const int bh = blockIdx.x;
    const long base = (long)bh * NNODE;
    const float ngc = ngb[bh], sc = sb[bh];

    float rk = (t < NNODE) ? (ng0[base + t] + ngc) : FLT_MAX;
    int   rp = t;

    for (int k = 2; k <= 512; k <<= 1) {
        for (int j = k >> 1; j > 0; j >>= 1) {
            const bool dir = ((t & k) == 0);
            const bool lower = ((t & j) == 0);
            float ok_; int op;
            if (j >= 64) {
                __syncthreads();            // protect prior reads of key/perm
                key[t] = rk; perm[t] = rp;
                __syncthreads();
                ok_ = key[t ^ j];
                op  = perm[t ^ j];
            } else {
                ok_ = __shfl_xor(rk, j, 64);
                op  = __shfl_xor(rp, j, 64);
            }
            const bool sw = lower ? ((rk > ok_) == dir) : ((ok_ > rk) == dir);
            if (sw) { rk = ok_; rp = op; }
        }
    }
    __syncthreads();                        // protect last cross-stage reads
    key[t] = rk; perm[t] = rp;              // publish sorted keys/perm
    if (t < NNODE) {
        w1[t] = __expf(rk);
        w2[t] = __expf(0.2f * rk);
    }
    __syncthreads();

    if (t < 16) {
        float a1 = 0.0f;
        for (int jj = 24; jj >= 0; --jj) {
            int j = t * 25 + jj;
            if (j < NNODE) { a1 += w1[j]; D1[j] = a1; }
        }
        CT1[t] = a1;
    } else if (t < 32) {
        int c = t - 16;
        float a2 = 0.0f;
        for (int jj = 0; jj < 25; ++jj) {
            int j = c * 25 + jj;
            if (j < NNODE) { D2[j] = a2; a2 += w2[j]; }
        }
        CT2[c] = a2;
    }
    __syncthreads();
    if (t < 16) {
        float off = 0.0f;
        for (int cc = t + 1; cc < 16; ++cc) off += CT1[cc];
        for (int jj = 0; jj < 25; ++jj) {
            int j = t * 25 + jj;
            if (j < NNODE) D1[j] += off;
        }
    } else if (t < 32) {
        int c = t - 16;
        float off = 0.0f;
        for (int cc = 0; cc < c; ++cc) off += CT2[cc];
        for (int jj = 0; jj < 25; ++jj) {
            int j = c * 25 + jj;
            if (j < NNODE) D2[j] += off;
        }
    } else if (t == 32) {
        D1[NNODE] = 0.0f;
    } else if (t == 33) {
        float tot = 0.0f;
        for (int cc = 0; cc < 16; ++cc) tot += CT2[cc];
        D2[NNODE] = tot;
    }
    __syncthreads();

    if (t < NNODE) {
        float sn = s0[base + t] + sc;
        float negs = -sn;
        int lo = 0, hi = NNODE;
        while (lo < hi) {
            int mid = (lo + hi) >> 1;
            if (key[mid] < negs) lo = mid + 1; else hi = mid;
        }
        float e1 = __expf(sn), e2 = __expf(0.2f * sn);
        float inv = __builtin_amdgcn_rcpf(e1 * D1[lo] + e2 * D2[lo]);
        ptG[base + t]  = (uint)perm[t] | ((uint)lo << 16);
        g12G[base + t] = make_float2(e1 * inv, e2 * inv);
        w12G[base + t] = make_float2(w1[t], w2[t]);
    }
}

// ---------------------------------------------------------------------------
// attn_scan: block = (og, bh); 16 o-cols, 1024 threads = 64 chunks x 16.
// 32 B/row gather, column-major LDS. Cross-chunk offsets via 6-step
// Hillis-Steele tree scans over CT (replaces 63-deep serial LDS loops).
// out = elu(g1*S1[t] + g2*S2[t] + zbK[b][col] + bias).
#define CHN 7    // chunk depth: 64*7 = 448 >= 392
#define NP  (NNODE + 1)
__global__ __launch_bounds__(1024)
void attn_scan(const ushort* __restrict__ xp, const uint* __restrict__ ptG,
               const float2* __restrict__ w12G, const float2* __restrict__ g12G,
               const float* __restrict__ zbK, const float* __restrict__ bias,
               float* __restrict__ out)
{
    __shared__ float  Vs[16 * NP];
    __shared__ float  S1[16 * NP];
    __shared__ float  w1s[NNODE], w2s[NNODE], g1s[NNODE], g2s[NNODE];
    __shared__ ushort perms[NNODE], tls[NNODE];
    __shared__ float  CT[64][17], CT2[64][17];
    __shared__ float  biasl[16];

    const int t  = threadIdx.x;
    const int og = blockIdx.x;          // 0..3
    const int bh = blockIdx.y;          // 0..431
    const int b  = bh >> 2, h = bh & 3;
    const long base = (long)bh * NNODE;
    const int c0 = h * 64 + og * 16;

    if (t < NNODE) {
        uint pt = ptG[base + t];
        perms[t] = (ushort)(pt & 0xFFFFu);
        tls[t]   = (ushort)(pt >> 16);
        float2 w = w12G[base + t];
        w1s[t] = w.x; w2s[t] = w.y;
    } else if (t >= 512 && t < 512 + NNODE) {
        int i = t - 512;
        float2 g = g12G[base + i];
        g1s[i] = g.x; g2s[i] = g.y;
    }
    if (t < 16) biasl[t] = bias[c0 + t] + zbK[b * 256 + c0 + t];
    __syncthreads();

    // gather: 2 x uint4 (8 bf16 each) per sorted row; column-major scatter
    if (t < NNODE * 2) {
        int j = t >> 1, q = (t & 1) * 8;
        int m = perms[j];
        u16x8 raw = *(const u16x8*)(xp + ((long)b * NNODE + m) * HO + c0 + q);
        #pragma unroll
        for (int oo = 0; oo < 8; ++oo) Vs[(q + oo) * NP + j] = bf2f(raw[oo]);
    }
    __syncthreads();

    const int c = t >> 4, o = t & 15;   // 64 chunks x 16 cols

    // S1: w1-weighted suffix sums within chunk
    {
        float acc = 0.0f;
        #pragma unroll
        for (int jj = CHN - 1; jj >= 0; --jj) {
            int j = c * CHN + jj;
            if (j < NNODE) {
                acc = fmaf(w1s[j], Vs[o * NP + j], acc);
                S1[o * NP + j] = acc;
            }
        }
        CT[c][o] = acc;
    }
    __syncthreads();
    // tree-scan CT into inclusive SUFFIX sums over c (6 steps)
    #pragma unroll
    for (int s = 1; s < 64; s <<= 1) {
        float add = (c + s < 64) ? CT[c + s][o] : 0.0f;
        __syncthreads();
        CT[c][o] += add;
        __syncthreads();
    }
    {
        float off = (c < 63) ? CT[c + 1][o] : 0.0f;
        #pragma unroll
        for (int jj = 0; jj < CHN; ++jj) {
            int j = c * CHN + jj;
            if (j < NNODE) S1[o * NP + j] += off;
        }
        if (c == 0) S1[o * NP + NNODE] = 0.0f;
    }
    // S2: w2-weighted exclusive prefix within chunk, in place over Vs
    {
        float acc = 0.0f;
        #pragma unroll
        for (int jj = 0; jj < CHN; ++jj) {
            int j = c * CHN + jj;
            if (j < NNODE) {
                float tmp = Vs[o * NP + j];
                Vs[o * NP + j] = acc;
                acc = fmaf(w2s[j], tmp, acc);
            }
        }
        CT2[c][o] = acc;
    }
    __syncthreads();
    // tree-scan CT2 into inclusive PREFIX sums over c (6 steps)
    #pragma unroll
    for (int s = 1; s < 64; s <<= 1) {
        float add = (c >= s) ? CT2[c - s][o] : 0.0f;
        __syncthreads();
        CT2[c][o] += add;
        __syncthreads();
    }
    {
        float off = (c > 0) ? CT2[c - 1][o] : 0.0f;
        #pragma unroll
        for (int jj = 0; jj < CHN; ++jj) {
            int j = c * CHN + jj;
            if (j < NNODE) Vs[o * NP + j] += off;
        }
        if (c == 63) Vs[o * NP + NNODE] = CT2[63][o];
    }
    __syncthreads();

    // emit: float4 per (row, col-quad)
    for (int idx = t; idx < NNODE * 4; idx += 1024) {
        int n = idx >> 2, q = (idx & 3) * 4;
        int tt = tls[n];
        float g1 = g1s[n], g2 = g2s[n];
        float r[4];
        #pragma unroll
        for (int rr = 0; rr < 4; ++rr) {
            int oo = q + rr;
            float v = g1 * S1[oo * NP + tt] + g2 * Vs[oo * NP + tt] + biasl[oo];
            r[rr] = (v > 0.0f) ? v : (__expf(v) - 1.0f);
        }
        *(float4*)(out + ((long)b * NNODE + n) * HO + c0 + q) =
            make_float4(r[0], r[1], r[2], r[3]);
    }
}

extern "C" void kernel_launch(void* const* d_in, const int* in_sizes, int n_in,
                              void* d_out, int out_size, void* d_ws, size_t ws_size,
                              hipStream_t stream) {
    const float* x     = (const float*)d_in[0];   // [108,392,256]
    const float* w_mlp = (const float*)d_in[2];   // [256,256]
    const float* b_mlp = (const float*)d_in[3];   // [256]
    const float* kern  = (const float*)d_in[4];   // [256,4,64] == [256,256]
    const float* ask   = (const float*)d_in[5];   // [64,4,1]
    const float* ank   = (const float*)d_in[6];   // [64,4,1]
    const float* bias  = (const float*)d_in[7];   // [256]
    float* out = (float*)d_out;

    const long TENS = (long)MROWS * IDIM;         // 10,838,016
    float*  s0    = (float*)d_ws;                 // [B,H,N]
    float*  ng0   = s0 + SGH;
    float*  zbacc = ng0 + SGH;                    // [B,256] atomically built
    float*  zbK   = zbacc + (long)BATCH * IDIM;   // [B,256]
    float*  sb    = zbK + (long)BATCH * HO;       // [B,H]
    float*  ngb   = sb + BATCH * HEADS;           // [B,H]
    float2* w12G  = (float2*)(ngb + BATCH * HEADS);
    float2* g12G  = w12G + SGH;
    uint*   ptG   = (uint*)(g12G + SGH);
    ushort* xp_bf = (ushort*)(ptG + SGH);         // [B,N,H*O] bf16 (xp0)
    ushort* wshuf = xp_bf + TENS;                 // [65536] frag-order w_mlp
    ushort* kshuf = wshuf + 65536;                // [65536] frag-order kernel

    dim3 blk(256);

    // 0) weight shuffle + zbacc zeroing (fused)
    wcvt<<<dim3(512), blk, 0, stream>>>(w_mlp, kern, wshuf, kshuf, zbacc);

    // 1) fused: mlp(sigmoid, LDS-only) -> col-sums -> xp0 + s0/ng0
    fused_gemm<<<dim3(13, BATCH), dim3(256), 0, stream>>>(
        x, wshuf, kshuf, b_mlp, zbacc, xp_bf, ask, ank, s0, ng0);

    // 2) zbK = (0.8*mean mlp) @ kernel + per-(b,h) projection constants
    zbk_k<<<dim3(BATCH), dim3(1024), 0, stream>>>(zbacc, kern, ask, ank, zbK, sb, ngb);

    // 3) attention stats: shfl-based bitonic sort + denominators + thresholds
    attn_stats<<<dim3(BATCH * HEADS), dim3(512), 0, stream>>>(
        s0, ng0, sb, ngb, ptG, w12G, g12G);

    // 4) attention scan: tree-scanned prefix/suffix sums + emit
    attn_scan<<<dim3(4, BATCH * HEADS), dim3(1024), 0, stream>>>(
        xp_bf, ptG, w12G, g12G, zbK, bias, out);
}

// Round 6
// 189.442 us; speedup vs baseline: 1.1202x; 1.0234x over previous
//
#include <hip/hip_runtime.h>
#include <hip/hip_bf16.h>
#include <math.h>
#include <float.h>

// Problem constants (fixed by setup_inputs)
#define BATCH 108
#define NNODE 392
#define IDIM  256
#define HEADS 4
#define ODIM  64
#define HO    256            // HEADS*ODIM
#define MROWS (BATCH*NNODE)  // 42336
#define SGH   (BATCH*HEADS*NNODE)  // 169344

typedef __attribute__((ext_vector_type(8))) short bf16x8;
typedef __attribute__((ext_vector_type(8))) unsigned short u16x8;
typedef __attribute__((ext_vector_type(4))) float f32x4;

// exact RNE f32->bf16 (known-good; do NOT replace with v_cvt_pk_bf16_f32 —
// R1 showed that instruction's rounding breaks the absmax check: 7.6e-2 vs 7.8e-3)
__device__ __forceinline__ ushort f2bf(float f) {
    unsigned u = __float_as_uint(f);
    unsigned r = (u + 0x7FFFu + ((u >> 16) & 1u)) >> 16;   // RNE
    return (ushort)r;
}
__device__ __forceinline__ float bf2f(ushort h) {
    return __uint_as_float(((unsigned)h) << 16);
}
// fast sigmoid: v_mul + v_exp + v_add + v_rcp (kept from R2: VALUBusy 31->20%)
__device__ __forceinline__ float fsigmoid(float x) {
    float e = __expf(-x);
    return __builtin_amdgcn_rcpf(1.0f + e);
}

#define MSTR 264   // LDS row stride (256 + 8 pad)

// weight fragment fetch from pre-shuffled layout (wg/lane from scope)
#define FRAG(src, jn, k0t) \
    (*(const bf16x8*)((src) + ((((wg * 4 + (jn)) * 8 + (k0t)) << 9)) + lane * 8))

// ---------------------------------------------------------------------------
// Fused double-GEMM — R6: 2-deep weight prefetch. R5 counters: MfmaUtil 9.5,
// VALUBusy 22, occ 24% -> latency-bound; 1-deep prefetch gives a load only
// ~40-100 cyc of cover vs ~200 cyc L2 latency -> stall every k0t step. 2-deep
// buffers (wreg[2][4], index k0t&1 = compile-time after unroll) give each
// load a full iteration in flight. VGPR 72->~90 stays in the <=128 tier.
// R4 lesson kept: no forced __launch_bounds__ min-waves (spills at 32 VGPR).
__global__ __launch_bounds__(256)
void fused_gemm(const float* __restrict__ x, const ushort* __restrict__ wshuf,
                const ushort* __restrict__ kshuf, const float* __restrict__ bmlp,
                float* __restrict__ zbacc, ushort* __restrict__ xp0,
                const float* __restrict__ askv, const float* __restrict__ ankv,
                float* __restrict__ s0, float* __restrict__ ng0)
{
    __shared__ __attribute__((aligned(16))) ushort AsMs[32 * MSTR]; // x bf16 / mlp bf16
    __shared__ float cs_lds[256];   // per-block mlp col sums (deferred atomic)

    const int t    = threadIdx.x;
    const int lane = t & 63;
    const int wg   = t >> 6;            // 0..3 col-group / head
    const int lr   = lane & 15, kq = lane >> 4;
    const int rb   = blockIdx.x;        // 0..12 row-block within batch
    const int b    = blockIdx.y;
    const int row0 = rb * 32;
    const long gbase = (long)b * NNODE;

    // 2-deep prefetch of phase-1 weight fragments (no LDS dep; overlaps staging)
    bf16x8 wreg[2][4];
    #pragma unroll
    for (int jn = 0; jn < 4; ++jn) {
        wreg[0][jn] = FRAG(wshuf, jn, 0);
        wreg[1][jn] = FRAG(wshuf, jn, 1);
    }

    // ---- stage 32x256 x block (fp32 -> bf16), coalesced ----
    {
        const float* xb = x + (gbase + row0) * 256;
        #pragma unroll
        for (int j = 0; j < 8; ++j) {
            int e4  = t + j * 256;
            int row = e4 >> 6;
            int col = (e4 & 63) * 4;
            float4 v = (row0 + row < NNODE)
                ? *(const float4*)(xb + (long)row * 256 + col)
                : make_float4(0.f, 0.f, 0.f, 0.f);
            *(ushort4*)&AsMs[row * MSTR + col] =
                make_ushort4(f2bf(v.x), f2bf(v.y), f2bf(v.z), f2bf(v.w));
        }
    }
    __syncthreads();                        // barrier 1

    f32x4 acc[4][2] = {};   // [jn][imL]

    // ---------------- phase 1: mlp = sigmoid(x @ W + b) ----------------
    {
        #pragma unroll
        for (int k0t = 0; k0t < 8; ++k0t) {
            bf16x8 xf0 = *(const bf16x8*)&AsMs[lr * MSTR + k0t * 32 + kq * 8];
            bf16x8 xf1 = *(const bf16x8*)&AsMs[(16 + lr) * MSTR + k0t * 32 + kq * 8];
            #pragma unroll
            for (int jn = 0; jn < 4; ++jn) {
                acc[jn][0] = __builtin_amdgcn_mfma_f32_16x16x32_bf16(
                    wreg[k0t & 1][jn], xf0, acc[jn][0], 0, 0, 0);
                acc[jn][1] = __builtin_amdgcn_mfma_f32_16x16x32_bf16(
                    wreg[k0t & 1][jn], xf1, acc[jn][1], 0, 0, 0);
            }
            if (k0t < 6) {
                #pragma unroll
                for (int jn = 0; jn < 4; ++jn)
                    wreg[k0t & 1][jn] = FRAG(wshuf, jn, k0t + 2);
            }
        }
    }

    // prefetch phase-2 buffer 0 (overlaps epilogue 1; drained at barrier 2)
    bf16x8 kreg[2][4];
    #pragma unroll
    for (int jn = 0; jn < 4; ++jn) kreg[0][jn] = FRAG(kshuf, jn, 0);

    __syncthreads();                        // barrier 2

    // ---- epilogue 1: sigmoid -> Ms (aliases x); col sums -> cs_lds ----
    {
        float4 bi[4];
        #pragma unroll
        for (int jn = 0; jn < 4; ++jn)
            bi[jn] = *(const float4*)(bmlp + 64 * wg + 16 * jn + 4 * kq);
        float cs[4][4] = {};
        #pragma unroll
        for (int imL = 0; imL < 2; ++imL) {
            const int r_ = 16 * imL + lr;
            const bool ok = row0 + r_ < NNODE;
            #pragma unroll
            for (int jn = 0; jn < 4; ++jn) {
                float v[4];
                v[0] = fsigmoid(acc[jn][imL][0] + bi[jn].x);
                v[1] = fsigmoid(acc[jn][imL][1] + bi[jn].y);
                v[2] = fsigmoid(acc[jn][imL][2] + bi[jn].z);
                v[3] = fsigmoid(acc[jn][imL][3] + bi[jn].w);
                *(ushort4*)&AsMs[r_ * MSTR + 64 * wg + 16 * jn + 4 * kq] =
                    make_ushort4(f2bf(v[0]), f2bf(v[1]), f2bf(v[2]), f2bf(v[3]));
                if (ok) {
                    cs[jn][0] += v[0]; cs[jn][1] += v[1];
                    cs[jn][2] += v[2]; cs[jn][3] += v[3];
                }
            }
        }
        #pragma unroll
        for (int jn = 0; jn < 4; ++jn)
            #pragma unroll
            for (int r = 0; r < 4; ++r) {
                float v = cs[jn][r];
                v += __shfl_xor(v, 1, 64);
                v += __shfl_xor(v, 2, 64);
                v += __shfl_xor(v, 4, 64);
                v += __shfl_xor(v, 8, 64);
                if (lr == 0)
                    cs_lds[64 * wg + 16 * jn + 4 * kq + r] = v;
            }
    }
    __syncthreads();                        // barrier 3

    // ---------------- phase 2: xp0 = 0.2 * (Ms @ K^T) ----------------
    #pragma unroll
    for (int jn = 0; jn < 4; ++jn)
        #pragma unroll
        for (int imL = 0; imL < 2; ++imL)
            acc[jn][imL] = f32x4{0.f, 0.f, 0.f, 0.f};

    // prefetch phase-2 buffer 1 (covered by k0t=0's LDS reads + MFMAs)
    #pragma unroll
    for (int jn = 0; jn < 4; ++jn) kreg[1][jn] = FRAG(kshuf, jn, 1);

    {
        #pragma unroll
        for (int k0t = 0; k0t < 8; ++k0t) {
            bf16x8 xf0 = *(const bf16x8*)&AsMs[lr * MSTR + k0t * 32 + kq * 8];
            bf16x8 xf1 = *(const bf16x8*)&AsMs[(16 + lr) * MSTR + k0t * 32 + kq * 8];
            #pragma unroll
            for (int jn = 0; jn < 4; ++jn) {
                acc[jn][0] = __builtin_amdgcn_mfma_f32_16x16x32_bf16(
                    kreg[k0t & 1][jn], xf0, acc[jn][0], 0, 0, 0);
                acc[jn][1] = __builtin_amdgcn_mfma_f32_16x16x32_bf16(
                    kreg[k0t & 1][jn], xf1, acc[jn][1], 0, 0, 0);
            }
            if (k0t < 6) {
                #pragma unroll
                for (int jn = 0; jn < 4; ++jn)
                    kreg[k0t & 1][jn] = FRAG(kshuf, jn, k0t + 2);
            }
        }
    }

    // ---- epilogue 2: xp0 stores + fused s0/ng0 projections ----
    {
        const int h = wg;
        float askr[4][4], ankr[4][4];
        #pragma unroll
        for (int jn = 0; jn < 4; ++jn)
            #pragma unroll
            for (int r = 0; r < 4; ++r) {
                int o = 16 * jn + 4 * kq + r;
                askr[jn][r] = askv[o * HEADS + h];
                ankr[jn][r] = ankv[o * HEADS + h];
            }
        #pragma unroll
        for (int imL = 0; imL < 2; ++imL) {
            const int r_ = 16 * imL + lr;
            const int lrow = row0 + r_;
            const bool ok = lrow < NNODE;
            float ps = 0.0f, pn = 0.0f;
            if (ok) {
                ushort* dst = xp0 + (gbase + lrow) * 256 + 64 * h + 4 * kq;
                #pragma unroll
                for (int jn = 0; jn < 4; ++jn) {
                    float v0 = 0.2f * acc[jn][imL][0];
                    float v1 = 0.2f * acc[jn][imL][1];
                    float v2 = 0.2f * acc[jn][imL][2];
                    float v3 = 0.2f * acc[jn][imL][3];
                    *(ushort4*)(dst + 16 * jn) =
                        make_ushort4(f2bf(v0), f2bf(v1), f2bf(v2), f2bf(v3));
                    ps += v0 * askr[jn][0] + v1 * askr[jn][1] +
                          v2 * askr[jn][2] + v3 * askr[jn][3];
                    pn += v0 * ankr[jn][0] + v1 * ankr[jn][1] +
                          v2 * ankr[jn][2] + v3 * ankr[jn][3];
                }
            }
            ps += __shfl_xor(ps, 16, 64);
            ps += __shfl_xor(ps, 32, 64);
            pn += __shfl_xor(pn, 16, 64);
            pn += __shfl_xor(pn, 32, 64);
            if (ok && kq == 0) {
                long si = ((long)b * HEADS + h) * NNODE + lrow;
                s0[si]  = ps;
                ng0[si] = pn;
            }
        }
    }

    // deferred zbacc accumulation (cs_lds complete since barrier 3 and
    // untouched afterwards; no barrier needed here)
    atomicAdd(&zbacc[b * 256 + t], cs_lds[t]);
}

// ---------------------------------------------------------------------------
// Weight transpose + bf16 + MFMA-fragment shuffle; also zeroes zbacc
// (blocks 0..107 cover BATCH*IDIM = 27648 floats) -> saves a memset dispatch.
__global__ __launch_bounds__(256)
void wcvt(const float* __restrict__ w_mlp, const float* __restrict__ kern,
          ushort* __restrict__ wshuf, ushort* __restrict__ kshuf,
          float* __restrict__ zbacc)
{
    if (blockIdx.x < BATCH)
        zbacc[blockIdx.x * 256 + threadIdx.x] = 0.0f;
    long idx = (long)(blockIdx.x & 255) * 256 + threadIdx.x;   // 0..65535
    const float* src = (blockIdx.x < 256) ? w_mlp : kern;
    ushort* dst = (blockIdx.x < 256) ? wshuf : kshuf;
    int e    = idx & 7;
    int lane = (int)(idx >> 3) & 63;
    int k0t  = (int)(idx >> 9) & 7;
    int jn   = (int)(idx >> 12) & 3;
    int g    = (int)(idx >> 14);
    int n = 64 * g + 16 * jn + (lane & 15);
    int k = 32 * k0t + (lane >> 4) * 8 + e;
    dst[idx] = f2bf(src[(long)k * 256 + n]);
}

// ---------------------------------------------------------------------------
// zbK[b,c] = (0.8/N * zbacc[b]) @ kernel; also per-(b,h) projection consts.
// 1024 threads: k split into 4 chunks of 64.
__global__ __launch_bounds__(1024)
void zbk_k(const float* __restrict__ zbacc, const float* __restrict__ kern,
           const float* __restrict__ askv, const float* __restrict__ ankv,
           float* __restrict__ zbK, float* __restrict__ sb,
           float* __restrict__ ngb)
{
    __shared__ float zrow[IDIM];
    __shared__ float part[4][IDIM];
    const int b = blockIdx.x, t = threadIdx.x;
    if (t < IDIM) zrow[t] = zbacc[b * 256 + t] * (0.8f / (float)NNODE);
    __syncthreads();
    const int c = t & 255, kc = t >> 8;
    float acc = 0.0f;
    #pragma unroll
    for (int kk = 0; kk < 64; ++kk) {
        int k = kc * 64 + kk;
        acc = fmaf(zrow[k], kern[(long)k * HO + c], acc);
    }
    part[kc][c] = acc;
    __syncthreads();
    if (t < IDIM) {
        float a = part[0][t] + part[1][t] + part[2][t] + part[3][t];
        zbK[b * 256 + t] = a;
        int h = t >> 6, o = t & 63;
        float ps = a * askv[o * HEADS + h];
        float pn = a * ankv[o * HEADS + h];
        #pragma unroll
        for (int off = 32; off; off >>= 1) {
            ps += __shfl_down(ps, off, 64);
            pn += __shfl_down(pn, off, 64);
        }
        if (o == 0) {
            sb[b * HEADS + h]  = ps;
            ngb[b * HEADS + h] = pn;
        }
    }
}

// ---------------------------------------------------------------------------
// attn_stats: per (b,h): keys = ng0 + ngb[bh]. R5: register-resident bitonic
// sort — 39 of 45 stages within-wave via __shfl_xor (no barrier); only the 6
// j>=64 stages go through LDS. Bit-identical to the LDS version.
__global__ __launch_bounds__(512)
void attn_stats(const float* __restrict__ s0, const float* __restrict__ ng0,
                const float* __restrict__ sb, const float* __restrict__ ngb,
                uint* __restrict__ ptG, float2* __restrict__ w12G,
                float2* __restrict__ g12G)
{
    __shared__ float key[512];
    __shared__ int   perm[512];
    __shared__ float w1[NNODE], w2[NNODE];
    __shared__ float D1[NNODE + 1], D2[NNODE + 1];
    __shared__ float CT1[16], CT2[16];

    const int t = threadIdx.x;
    const int bh = blockIdx.x;
    const long base = (long)bh * NNODE;
    const float ngc = ngb[bh], sc = sb[bh];

    float rk = (t < NNODE) ? (ng0[base + t] + ngc) : FLT_MAX;
    int   rp = t;

    for (int k = 2; k <= 512; k <<= 1) {
        for (int j = k >> 1; j > 0; j >>= 1) {
            const bool dir = ((t & k) == 0);
            const bool lower = ((t & j) == 0);
            float ok_; int op;
            if (j >= 64) {
                __syncthreads();            // protect prior reads of key/perm
                key[t] = rk; perm[t] = rp;
                __syncthreads();
                ok_ = key[t ^ j];
                op  = perm[t ^ j];
            } else {
                ok_ = __shfl_xor(rk, j, 64);
                op  = __shfl_xor(rp, j, 64);
            }
            const bool sw = lower ? ((rk > ok_) == dir) : ((ok_ > rk) == dir);
            if (sw) { rk = ok_; rp = op; }
        }
    }
    __syncthreads();                        // protect last cross-stage reads
    key[t] = rk; perm[t] = rp;              // publish sorted keys/perm
    if (t < NNODE) {
        w1[t] = __expf(rk);
        w2[t] = __expf(0.2f * rk);
    }
    __syncthreads();

    if (t < 16) {
        float a1 = 0.0f;
        for (int jj = 24; jj >= 0; --jj) {
            int j = t * 25 + jj;
            if (j < NNODE) { a1 += w1[j]; D1[j] = a1; }
        }
        CT1[t] = a1;
    } else if (t < 32) {
        int c = t - 16;
        float a2 = 0.0f;
        for (int jj = 0; jj < 25; ++jj) {
            int j = c * 25 + jj;
            if (j < NNODE) { D2[j] = a2; a2 += w2[j]; }
        }
        CT2[c] = a2;
    }
    __syncthreads();
    if (t < 16) {
        float off = 0.0f;
        for (int cc = t + 1; cc < 16; ++cc) off += CT1[cc];
        for (int jj = 0; jj < 25; ++jj) {
            int j = t * 25 + jj;
            if (j < NNODE) D1[j] += off;
        }
    } else if (t < 32) {
        int c = t - 16;
        float off = 0.0f;
        for (int cc = 0; cc < c; ++cc) off += CT2[cc];
        for (int jj = 0; jj < 25; ++jj) {
            int j = c * 25 + jj;
            if (j < NNODE) D2[j] += off;
        }
    } else if (t == 32) {
        D1[NNODE] = 0.0f;
    } else if (t == 33) {
        float tot = 0.0f;
        for (int cc = 0; cc < 16; ++cc) tot += CT2[cc];
        D2[NNODE] = tot;
    }
    __syncthreads();

    if (t < NNODE) {
        float sn = s0[base + t] + sc;
        float negs = -sn;
        int lo = 0, hi = NNODE;
        while (lo < hi) {
            int mid = (lo + hi) >> 1;
            if (key[mid] < negs) lo = mid + 1; else hi = mid;
        }
        float e1 = __expf(sn), e2 = __expf(0.2f * sn);
        float inv = __builtin_amdgcn_rcpf(e1 * D1[lo] + e2 * D2[lo]);
        ptG[base + t]  = (uint)perm[t] | ((uint)lo << 16);
        g12G[base + t] = make_float2(e1 * inv, e2 * inv);
        w12G[base + t] = make_float2(w1[t], w2[t]);
    }
}

// ---------------------------------------------------------------------------
// attn_scan: block = (og, bh); 16 o-cols, 1024 threads = 64 chunks x 16.
// R6: cross-chunk CT/CT2 scans done wave-parallel — wave w owns column o=w,
// 64 lanes = 64 chunks, 6 shfl steps in-register. Same Hillis-Steele
// recurrence as the old LDS tree (bit-identical); barriers 24 -> 4.
#define CHN 7    // chunk depth: 64*7 = 448 >= 392
#define NP  (NNODE + 1)
__global__ __launch_bounds__(1024)
void attn_scan(const ushort* __restrict__ xp, const uint* __restrict__ ptG,
               const float2* __restrict__ w12G, const float2* __restrict__ g12G,
               const float* __restrict__ zbK, const float* __restrict__ bias,
               float* __restrict__ out)
{
    __shared__ float  Vs[16 * NP];
    __shared__ float  S1[16 * NP];
    __shared__ float  w1s[NNODE], w2s[NNODE], g1s[NNODE], g2s[NNODE];
    __shared__ ushort perms[NNODE], tls[NNODE];
    __shared__ float  CT[64][17], CT2[64][17];
    __shared__ float  biasl[16];

    const int t  = threadIdx.x;
    const int og = blockIdx.x;          // 0..3
    const int bh = blockIdx.y;          // 0..431
    const int b  = bh >> 2, h = bh & 3;
    const long base = (long)bh * NNODE;
    const int c0 = h * 64 + og * 16;

    if (t < NNODE) {
        uint pt = ptG[base + t];
        perms[t] = (ushort)(pt & 0xFFFFu);
        tls[t]   = (ushort)(pt >> 16);
        float2 w = w12G[base + t];
        w1s[t] = w.x; w2s[t] = w.y;
    } else if (t >= 512 && t < 512 + NNODE) {
        int i = t - 512;
        float2 g = g12G[base + i];
        g1s[i] = g.x; g2s[i] = g.y;
    }
    if (t < 16) biasl[t] = bias[c0 + t] + zbK[b * 256 + c0 + t];
    __syncthreads();

    // gather: 2 x uint4 (8 bf16 each) per sorted row; column-major scatter
    if (t < NNODE * 2) {
        int j = t >> 1, q = (t & 1) * 8;
        int m = perms[j];
        u16x8 raw = *(const u16x8*)(xp + ((long)b * NNODE + m) * HO + c0 + q);
        #pragma unroll
        for (int oo = 0; oo < 8; ++oo) Vs[(q + oo) * NP + j] = bf2f(raw[oo]);
    }
    __syncthreads();

    const int c = t >> 4, o = t & 15;   // 64 chunks x 16 cols

    // S1: w1-weighted suffix sums within chunk
    {
        float acc = 0.0f;
        #pragma unroll
        for (int jj = CHN - 1; jj >= 0; --jj) {
            int j = c * CHN + jj;
            if (j < NNODE) {
                acc = fmaf(w1s[j], Vs[o * NP + j], acc);
                S1[o * NP + j] = acc;
            }
        }
        CT[c][o] = acc;
    }
    __syncthreads();
    // wave-parallel suffix scan of CT: wave w scans column w over 64 chunks
    {
        const int w = t >> 6, ln = t & 63;
        float v = CT[ln][w];
        #pragma unroll
        for (int s = 1; s < 64; s <<= 1) {
            float tmp = __shfl_down(v, s, 64);
            if (ln + s < 64) v += tmp;
        }
        CT[ln][w] = v;
    }
    __syncthreads();
    {
        float off = (c < 63) ? CT[c + 1][o] : 0.0f;
        #pragma unroll
        for (int jj = 0; jj < CHN; ++jj) {
            int j = c * CHN + jj;
            if (j < NNODE) S1[o * NP + j] += off;
        }
        if (c == 0) S1[o * NP + NNODE] = 0.0f;
    }
    // S2: w2-weighted exclusive prefix within chunk, in place over Vs
    {
        float acc = 0.0f;
        #pragma unroll
        for (int jj = 0; jj < CHN; ++jj) {
            int j = c * CHN + jj;
            if (j < NNODE) {
                float tmp = Vs[o * NP + j];
                Vs[o * NP + j] = acc;
                acc = fmaf(w2s[j], tmp, acc);
            }
        }
        CT2[c][o] = acc;
    }
    __syncthreads();
    // wave-parallel prefix scan of CT2: wave w scans column w over 64 chunks
    {
        const int w = t >> 6, ln = t & 63;
        float v = CT2[ln][w];
        #pragma unroll
        for (int s = 1; s < 64; s <<= 1) {
            float tmp = __shfl_up(v, s, 64);
            if (ln >= s) v += tmp;
        }
        CT2[ln][w] = v;
    }
    __syncthreads();
    {
        float off = (c > 0) ? CT2[c - 1][o] : 0.0f;
        #pragma unroll
        for (int jj = 0; jj < CHN; ++jj) {
            int j = c * CHN + jj;
            if (j < NNODE) Vs[o * NP + j] += off;
        }
        if (c == 63) Vs[o * NP + NNODE] = CT2[63][o];
    }
    __syncthreads();

    // emit: float4 per (row, col-quad)
    for (int idx = t; idx < NNODE * 4; idx += 1024) {
        int n = idx >> 2, q = (idx & 3) * 4;
        int tt = tls[n];
        float g1 = g1s[n], g2 = g2s[n];
        float r[4];
        #pragma unroll
        for (int rr = 0; rr < 4; ++rr) {
            int oo = q + rr;
            float v = g1 * S1[oo * NP + tt] + g2 * Vs[oo * NP + tt] + biasl[oo];
            r[rr] = (v > 0.0f) ? v : (__expf(v) - 1.0f);
        }
        *(float4*)(out + ((long)b * NNODE + n) * HO + c0 + q) =
            make_float4(r[0], r[1], r[2], r[3]);
    }
}

extern "C" void kernel_launch(void* const* d_in, const int* in_sizes, int n_in,
                              void* d_out, int out_size, void* d_ws, size_t ws_size,
                              hipStream_t stream) {
    const float* x     = (const float*)d_in[0];   // [108,392,256]
    const float* w_mlp = (const float*)d_in[2];   // [256,256]
    const float* b_mlp = (const float*)d_in[3];   // [256]
    const float* kern  = (const float*)d_in[4];   // [256,4,64] == [256,256]
    const float* ask   = (const float*)d_in[5];   // [64,4,1]
    const float* ank   = (const float*)d_in[6];   // [64,4,1]
    const float* bias  = (const float*)d_in[7];   // [256]
    float* out = (float*)d_out;

    const long TENS = (long)MROWS * IDIM;         // 10,838,016
    float*  s0    = (float*)d_ws;                 // [B,H,N]
    float*  ng0   = s0 + SGH;
    float*  zbacc = ng0 + SGH;                    // [B,256] atomically built
    float*  zbK   = zbacc + (long)BATCH * IDIM;   // [B,256]
    float*  sb    = zbK + (long)BATCH * HO;       // [B,H]
    float*  ngb   = sb + BATCH * HEADS;           // [B,H]
    float2* w12G  = (float2*)(ngb + BATCH * HEADS);
    float2* g12G  = w12G + SGH;
    uint*   ptG   = (uint*)(g12G + SGH);
    ushort* xp_bf = (ushort*)(ptG + SGH);         // [B,N,H*O] bf16 (xp0)
    ushort* wshuf = xp_bf + TENS;                 // [65536] frag-order w_mlp
    ushort* kshuf = wshuf + 65536;                // [65536] frag-order kernel

    dim3 blk(256);

    // 0) weight shuffle + zbacc zeroing (fused)
    wcvt<<<dim3(512), blk, 0, stream>>>(w_mlp, kern, wshuf, kshuf, zbacc);

    // 1) fused: mlp(sigmoid, LDS-only) -> col-sums -> xp0 + s0/ng0
    fused_gemm<<<dim3(13, BATCH), dim3(256), 0, stream>>>(
        x, wshuf, kshuf, b_mlp, zbacc, xp_bf, ask, ank, s0, ng0);

    // 2) zbK = (0.8*mean mlp) @ kernel + per-(b,h) projection constants
    zbk_k<<<dim3(BATCH), dim3(1024), 0, stream>>>(zbacc, kern, ask, ank, zbK, sb, ngb);

    // 3) attention stats: shfl-based bitonic sort + denominators + thresholds
    attn_stats<<<dim3(BATCH * HEADS), dim3(512), 0, stream>>>(
        s0, ng0, sb, ngb, ptG, w12G, g12G);

    // 4) attention scan: wave-parallel cross-chunk scans + emit
    attn_scan<<<dim3(4, BATCH * HEADS), dim3(1024), 0, stream>>>(
        xp_bf, ptG, w12G, g12G, zbK, bias, out);
}

// Round 7
// 177.363 us; speedup vs baseline: 1.1965x; 1.0681x over previous
//
#include <hip/hip_runtime.h>
#include <hip/hip_bf16.h>
#include <math.h>
#include <float.h>

// Problem constants (fixed by setup_inputs)
#define BATCH 108
#define NNODE 392
#define IDIM  256
#define HEADS 4
#define ODIM  64
#define HO    256            // HEADS*ODIM
#define MROWS (BATCH*NNODE)  // 42336
#define SGH   (BATCH*HEADS*NNODE)  // 169344

typedef __attribute__((ext_vector_type(8))) short bf16x8;
typedef __attribute__((ext_vector_type(8))) unsigned short u16x8;
typedef __attribute__((ext_vector_type(4))) float f32x4;

// exact RNE f32->bf16 (known-good; do NOT replace with v_cvt_pk_bf16_f32 —
// R1 showed that instruction's rounding breaks the absmax check: 7.6e-2 vs 7.8e-3)
__device__ __forceinline__ ushort f2bf(float f) {
    unsigned u = __float_as_uint(f);
    unsigned r = (u + 0x7FFFu + ((u >> 16) & 1u)) >> 16;   // RNE
    return (ushort)r;
}
__device__ __forceinline__ float bf2f(ushort h) {
    return __uint_as_float(((unsigned)h) << 16);
}
// fast sigmoid: v_mul + v_exp + v_add + v_rcp (kept from R2: VALUBusy 31->20%)
__device__ __forceinline__ float fsigmoid(float x) {
    float e = __expf(-x);
    return __builtin_amdgcn_rcpf(1.0f + e);
}

#define MSTR 264   // LDS row stride (256 + 8 pad)

// weight fragment fetch from pre-shuffled layout (wg/lane from scope)
#define FRAG(src, jn, k0t) \
    (*(const bf16x8*)((src) + ((((wg * 4 + (jn)) * 8 + (k0t)) << 9)) + lane * 8))

// ---------------------------------------------------------------------------
// Fused double-GEMM — unchanged from R6 (stable ~44 µs; R3-R6 attempts to
// move it — retile, launch_bounds, barrier-drain, prefetch depth — each <10%;
// occupancy arithmetic says ~2 blocks/CU resident for unexplained reasons;
// not hammering further without a verified mechanism).
__global__ __launch_bounds__(256)
void fused_gemm(const float* __restrict__ x, const ushort* __restrict__ wshuf,
                const ushort* __restrict__ kshuf, const float* __restrict__ bmlp,
                float* __restrict__ zbacc, ushort* __restrict__ xp0,
                const float* __restrict__ askv, const float* __restrict__ ankv,
                float* __restrict__ s0, float* __restrict__ ng0)
{
    __shared__ __attribute__((aligned(16))) ushort AsMs[32 * MSTR]; // x bf16 / mlp bf16
    __shared__ float cs_lds[256];   // per-block mlp col sums (deferred atomic)

    const int t    = threadIdx.x;
    const int lane = t & 63;
    const int wg   = t >> 6;            // 0..3 col-group / head
    const int lr   = lane & 15, kq = lane >> 4;
    const int rb   = blockIdx.x;        // 0..12 row-block within batch
    const int b    = blockIdx.y;
    const int row0 = rb * 32;
    const long gbase = (long)b * NNODE;

    // 2-deep prefetch of phase-1 weight fragments (no LDS dep; overlaps staging)
    bf16x8 wreg[2][4];
    #pragma unroll
    for (int jn = 0; jn < 4; ++jn) {
        wreg[0][jn] = FRAG(wshuf, jn, 0);
        wreg[1][jn] = FRAG(wshuf, jn, 1);
    }

    // ---- stage 32x256 x block (fp32 -> bf16), coalesced ----
    {
        const float* xb = x + (gbase + row0) * 256;
        #pragma unroll
        for (int j = 0; j < 8; ++j) {
            int e4  = t + j * 256;
            int row = e4 >> 6;
            int col = (e4 & 63) * 4;
            float4 v = (row0 + row < NNODE)
                ? *(const float4*)(xb + (long)row * 256 + col)
                : make_float4(0.f, 0.f, 0.f, 0.f);
            *(ushort4*)&AsMs[row * MSTR + col] =
                make_ushort4(f2bf(v.x), f2bf(v.y), f2bf(v.z), f2bf(v.w));
        }
    }
    __syncthreads();                        // barrier 1

    f32x4 acc[4][2] = {};   // [jn][imL]

    // ---------------- phase 1: mlp = sigmoid(x @ W + b) ----------------
    {
        #pragma unroll
        for (int k0t = 0; k0t < 8; ++k0t) {
            bf16x8 xf0 = *(const bf16x8*)&AsMs[lr * MSTR + k0t * 32 + kq * 8];
            bf16x8 xf1 = *(const bf16x8*)&AsMs[(16 + lr) * MSTR + k0t * 32 + kq * 8];
            #pragma unroll
            for (int jn = 0; jn < 4; ++jn) {
                acc[jn][0] = __builtin_amdgcn_mfma_f32_16x16x32_bf16(
                    wreg[k0t & 1][jn], xf0, acc[jn][0], 0, 0, 0);
                acc[jn][1] = __builtin_amdgcn_mfma_f32_16x16x32_bf16(
                    wreg[k0t & 1][jn], xf1, acc[jn][1], 0, 0, 0);
            }
            if (k0t < 6) {
                #pragma unroll
                for (int jn = 0; jn < 4; ++jn)
                    wreg[k0t & 1][jn] = FRAG(wshuf, jn, k0t + 2);
            }
        }
    }

    // prefetch phase-2 buffer 0 (overlaps epilogue 1; drained at barrier 2)
    bf16x8 kreg[2][4];
    #pragma unroll
    for (int jn = 0; jn < 4; ++jn) kreg[0][jn] = FRAG(kshuf, jn, 0);

    __syncthreads();                        // barrier 2

    // ---- epilogue 1: sigmoid -> Ms (aliases x); col sums -> cs_lds ----
    {
        float4 bi[4];
        #pragma unroll
        for (int jn = 0; jn < 4; ++jn)
            bi[jn] = *(const float4*)(bmlp + 64 * wg + 16 * jn + 4 * kq);
        float cs[4][4] = {};
        #pragma unroll
        for (int imL = 0; imL < 2; ++imL) {
            const int r_ = 16 * imL + lr;
            const bool ok = row0 + r_ < NNODE;
            #pragma unroll
            for (int jn = 0; jn < 4; ++jn) {
                float v[4];
                v[0] = fsigmoid(acc[jn][imL][0] + bi[jn].x);
                v[1] = fsigmoid(acc[jn][imL][1] + bi[jn].y);
                v[2] = fsigmoid(acc[jn][imL][2] + bi[jn].z);
                v[3] = fsigmoid(acc[jn][imL][3] + bi[jn].w);
                *(ushort4*)&AsMs[r_ * MSTR + 64 * wg + 16 * jn + 4 * kq] =
                    make_ushort4(f2bf(v[0]), f2bf(v[1]), f2bf(v[2]), f2bf(v[3]));
                if (ok) {
                    cs[jn][0] += v[0]; cs[jn][1] += v[1];
                    cs[jn][2] += v[2]; cs[jn][3] += v[3];
                }
            }
        }
        #pragma unroll
        for (int jn = 0; jn < 4; ++jn)
            #pragma unroll
            for (int r = 0; r < 4; ++r) {
                float v = cs[jn][r];
                v += __shfl_xor(v, 1, 64);
                v += __shfl_xor(v, 2, 64);
                v += __shfl_xor(v, 4, 64);
                v += __shfl_xor(v, 8, 64);
                if (lr == 0)
                    cs_lds[64 * wg + 16 * jn + 4 * kq + r] = v;
            }
    }
    __syncthreads();                        // barrier 3

    // ---------------- phase 2: xp0 = 0.2 * (Ms @ K^T) ----------------
    #pragma unroll
    for (int jn = 0; jn < 4; ++jn)
        #pragma unroll
        for (int imL = 0; imL < 2; ++imL)
            acc[jn][imL] = f32x4{0.f, 0.f, 0.f, 0.f};

    // prefetch phase-2 buffer 1 (covered by k0t=0's LDS reads + MFMAs)
    #pragma unroll
    for (int jn = 0; jn < 4; ++jn) kreg[1][jn] = FRAG(kshuf, jn, 1);

    {
        #pragma unroll
        for (int k0t = 0; k0t < 8; ++k0t) {
            bf16x8 xf0 = *(const bf16x8*)&AsMs[lr * MSTR + k0t * 32 + kq * 8];
            bf16x8 xf1 = *(const bf16x8*)&AsMs[(16 + lr) * MSTR + k0t * 32 + kq * 8];
            #pragma unroll
            for (int jn = 0; jn < 4; ++jn) {
                acc[jn][0] = __builtin_amdgcn_mfma_f32_16x16x32_bf16(
                    kreg[k0t & 1][jn], xf0, acc[jn][0], 0, 0, 0);
                acc[jn][1] = __builtin_amdgcn_mfma_f32_16x16x32_bf16(
                    kreg[k0t & 1][jn], xf1, acc[jn][1], 0, 0, 0);
            }
            if (k0t < 6) {
                #pragma unroll
                for (int jn = 0; jn < 4; ++jn)
                    kreg[k0t & 1][jn] = FRAG(kshuf, jn, k0t + 2);
            }
        }
    }

    // ---- epilogue 2: xp0 stores + fused s0/ng0 projections ----
    {
        const int h = wg;
        float askr[4][4], ankr[4][4];
        #pragma unroll
        for (int jn = 0; jn < 4; ++jn)
            #pragma unroll
            for (int r = 0; r < 4; ++r) {
                int o = 16 * jn + 4 * kq + r;
                askr[jn][r] = askv[o * HEADS + h];
                ankr[jn][r] = ankv[o * HEADS + h];
            }
        #pragma unroll
        for (int imL = 0; imL < 2; ++imL) {
            const int r_ = 16 * imL + lr;
            const int lrow = row0 + r_;
            const bool ok = lrow < NNODE;
            float ps = 0.0f, pn = 0.0f;
            if (ok) {
                ushort* dst = xp0 + (gbase + lrow) * 256 + 64 * h + 4 * kq;
                #pragma unroll
                for (int jn = 0; jn < 4; ++jn) {
                    float v0 = 0.2f * acc[jn][imL][0];
                    float v1 = 0.2f * acc[jn][imL][1];
                    float v2 = 0.2f * acc[jn][imL][2];
                    float v3 = 0.2f * acc[jn][imL][3];
                    *(ushort4*)(dst + 16 * jn) =
                        make_ushort4(f2bf(v0), f2bf(v1), f2bf(v2), f2bf(v3));
                    ps += v0 * askr[jn][0] + v1 * askr[jn][1] +
                          v2 * askr[jn][2] + v3 * askr[jn][3];
                    pn += v0 * ankr[jn][0] + v1 * ankr[jn][1] +
                          v2 * ankr[jn][2] + v3 * ankr[jn][3];
                }
            }
            ps += __shfl_xor(ps, 16, 64);
            ps += __shfl_xor(ps, 32, 64);
            pn += __shfl_xor(pn, 16, 64);
            pn += __shfl_xor(pn, 32, 64);
            if (ok && kq == 0) {
                long si = ((long)b * HEADS + h) * NNODE + lrow;
                s0[si]  = ps;
                ng0[si] = pn;
            }
        }
    }

    // deferred zbacc accumulation (cs_lds complete since barrier 3 and
    // untouched afterwards; no barrier needed here)
    atomicAdd(&zbacc[b * 256 + t], cs_lds[t]);
}

// ---------------------------------------------------------------------------
// Weight transpose + bf16 + MFMA-fragment shuffle; also zeroes zbacc
// (blocks 0..107 cover BATCH*IDIM = 27648 floats) -> saves a memset dispatch.
__global__ __launch_bounds__(256)
void wcvt(const float* __restrict__ w_mlp, const float* __restrict__ kern,
          ushort* __restrict__ wshuf, ushort* __restrict__ kshuf,
          float* __restrict__ zbacc)
{
    if (blockIdx.x < BATCH)
        zbacc[blockIdx.x * 256 + threadIdx.x] = 0.0f;
    long idx = (long)(blockIdx.x & 255) * 256 + threadIdx.x;   // 0..65535
    const float* src = (blockIdx.x < 256) ? w_mlp : kern;
    ushort* dst = (blockIdx.x < 256) ? wshuf : kshuf;
    int e    = idx & 7;
    int lane = (int)(idx >> 3) & 63;
    int k0t  = (int)(idx >> 9) & 7;
    int jn   = (int)(idx >> 12) & 3;
    int g    = (int)(idx >> 14);
    int n = 64 * g + 16 * jn + (lane & 15);
    int k = 32 * k0t + (lane >> 4) * 8 + e;
    dst[idx] = f2bf(src[(long)k * 256 + n]);
}

// ---------------------------------------------------------------------------
// attn_stats — R7: zbk_k folded in (computes its own sc/ngc from zbacc@kern,
// ~16k fma over 512 threads) and the serial 32-thread D1/D2 chunk scans
// replaced by wave-shfl scans (R6-proven pattern): inclusive suffix (D1) /
// exclusive prefix (D2) over 512 elems = 6 shfl steps + 8-entry cross-wave
// combine. Reassociation error ~1e-7 rel; enters softmax as constant shifts
// and leaky_relu is continuous at the threshold boundary -> safe.
__global__ __launch_bounds__(512)
void attn_stats(const float* __restrict__ s0, const float* __restrict__ ng0,
                const float* __restrict__ zbacc, const float* __restrict__ kern,
                const float* __restrict__ askv, const float* __restrict__ ankv,
                uint* __restrict__ ptG, float2* __restrict__ w12G,
                float2* __restrict__ g12G)
{
    __shared__ float key[512];
    __shared__ int   perm[512];
    __shared__ float w1[NNODE], w2[NNODE];
    __shared__ float D1[NNODE + 1], D2[NNODE + 1];
    __shared__ float zsh[IDIM];
    __shared__ float partK[8][64];
    __shared__ float wsumA[8], wsumB[8];
    __shared__ float scs[2];

    const int t = threadIdx.x;
    const int bh = blockIdx.x;
    const int b = bh >> 2, h = bh & 3;
    const long base = (long)bh * NNODE;
    const int ln = t & 63, w = t >> 6;

    // ---- fold of zbk_k: sc = (0.8/N * zbacc[b]) @ kern[:,h*64+o] . ask ----
    if (t < IDIM) zsh[t] = zbacc[b * 256 + t] * (0.8f / (float)NNODE);
    __syncthreads();
    {
        const int o = ln, kc = w;           // 8 chunks x 32 k
        float p = 0.0f;
        #pragma unroll
        for (int kk = 0; kk < 32; ++kk) {
            int k = kc * 32 + kk;
            p = fmaf(zsh[k], kern[(long)k * HO + h * 64 + o], p);
        }
        partK[kc][o] = p;
    }
    __syncthreads();
    if (t < 64) {
        float zk = 0.0f;
        #pragma unroll
        for (int kc = 0; kc < 8; ++kc) zk += partK[kc][t];
        float ps = zk * askv[t * HEADS + h];
        float pn = zk * ankv[t * HEADS + h];
        #pragma unroll
        for (int off = 32; off; off >>= 1) {
            ps += __shfl_down(ps, off, 64);
            pn += __shfl_down(pn, off, 64);
        }
        if (t == 0) { scs[0] = ps; scs[1] = pn; }
    }
    __syncthreads();
    const float sc = scs[0], ngc = scs[1];

    // ---- register-resident bitonic sort (R5) ----
    float rk = (t < NNODE) ? (ng0[base + t] + ngc) : FLT_MAX;
    int   rp = t;

    for (int k = 2; k <= 512; k <<= 1) {
        for (int j = k >> 1; j > 0; j >>= 1) {
            const bool dir = ((t & k) == 0);
            const bool lower = ((t & j) == 0);
            float ok_; int op;
            if (j >= 64) {
                __syncthreads();            // protect prior reads of key/perm
                key[t] = rk; perm[t] = rp;
                __syncthreads();
                ok_ = key[t ^ j];
                op  = perm[t ^ j];
            } else {
                ok_ = __shfl_xor(rk, j, 64);
                op  = __shfl_xor(rp, j, 64);
            }
            const bool sw = lower ? ((rk > ok_) == dir) : ((ok_ > rk) == dir);
            if (sw) { rk = ok_; rp = op; }
        }
    }
    __syncthreads();                        // protect last cross-stage reads
    key[t] = rk; perm[t] = rp;              // publish sorted keys/perm

    // ---- weights + wave-shfl suffix/prefix scans ----
    const float w1v = (t < NNODE) ? __expf(rk) : 0.0f;
    const float w2v = (t < NNODE) ? __expf(0.2f * rk) : 0.0f;
    if (t < NNODE) { w1[t] = w1v; w2[t] = w2v; }

    // D1: inclusive suffix sum of w1v
    float v1 = w1v;
    #pragma unroll
    for (int s = 1; s < 64; s <<= 1) {
        float tmp = __shfl_down(v1, s, 64);
        if (ln + s < 64) v1 += tmp;
    }
    // D2: exclusive prefix sum of w2v (shift then inclusive scan = exact)
    float v2 = (ln >= 1) ? __shfl_up(w2v, 1, 64) : 0.0f;
    #pragma unroll
    for (int s = 1; s < 64; s <<= 1) {
        float tmp = __shfl_up(v2, s, 64);
        if (ln >= s) v2 += tmp;
    }
    const float wt2 = __shfl(v2, 63, 64) + __shfl(w2v, 63, 64); // wave total w2
    if (ln == 0) { wsumA[w] = v1; wsumB[w] = wt2; }             // v1@ln0 = wave total w1
    __syncthreads();
    {
        float off1 = 0.0f, off2 = 0.0f;
        for (int ww = w + 1; ww < 8; ++ww) off1 += wsumA[ww];
        for (int ww = 0; ww < w; ++ww)     off2 += wsumB[ww];
        if (t < NNODE) {
            D1[t] = v1 + off1;
            D2[t] = v2 + off2;
        }
        if (t == 0) {
            D1[NNODE] = 0.0f;
            float tot = 0.0f;
            #pragma unroll
            for (int ww = 0; ww < 8; ++ww) tot += wsumB[ww];
            D2[NNODE] = tot;
        }
    }
    __syncthreads();

    if (t < NNODE) {
        float sn = s0[base + t] + sc;
        float negs = -sn;
        int lo = 0, hi = NNODE;
        while (lo < hi) {
            int mid = (lo + hi) >> 1;
            if (key[mid] < negs) lo = mid + 1; else hi = mid;
        }
        float e1 = __expf(sn), e2 = __expf(0.2f * sn);
        float inv = __builtin_amdgcn_rcpf(e1 * D1[lo] + e2 * D2[lo]);
        ptG[base + t]  = (uint)perm[t] | ((uint)lo << 16);
        g12G[base + t] = make_float2(e1 * inv, e2 * inv);
        w12G[base + t] = make_float2(w1[t], w2[t]);
    }
}

// ---------------------------------------------------------------------------
// attn_scan — R7: zbK folded into biasl (16x256 dot via 256-thread partials
// in a dedicated bp[] array; no extra barrier — reuses the existing two).
// Cross-chunk scans wave-parallel (R6).
#define CHN 7    // chunk depth: 64*7 = 448 >= 392
#define NP  (NNODE + 1)
__global__ __launch_bounds__(1024)
void attn_scan(const ushort* __restrict__ xp, const uint* __restrict__ ptG,
               const float2* __restrict__ w12G, const float2* __restrict__ g12G,
               const float* __restrict__ zbacc, const float* __restrict__ kern,
               const float* __restrict__ bias, float* __restrict__ out)
{
    __shared__ float  Vs[16 * NP];
    __shared__ float  S1[16 * NP];
    __shared__ float  w1s[NNODE], w2s[NNODE], g1s[NNODE], g2s[NNODE];
    __shared__ ushort perms[NNODE], tls[NNODE];
    __shared__ float  CT[64][17], CT2[64][17];
    __shared__ float  zsh[IDIM];
    __shared__ float  bp[16][17];
    __shared__ float  biasl[16];

    const int t  = threadIdx.x;
    const int og = blockIdx.x;          // 0..3
    const int bh = blockIdx.y;          // 0..431
    const int b  = bh >> 2, h = bh & 3;
    const long base = (long)bh * NNODE;
    const int c0 = h * 64 + og * 16;

    if (t < NNODE) {
        uint pt = ptG[base + t];
        perms[t] = (ushort)(pt & 0xFFFFu);
        tls[t]   = (ushort)(pt >> 16);
        float2 w = w12G[base + t];
        w1s[t] = w.x; w2s[t] = w.y;
    } else if (t >= 512 && t < 512 + NNODE) {
        int i = t - 512;
        float2 g = g12G[base + i];
        g1s[i] = g.x; g2s[i] = g.y;
    }
    if (t < IDIM) zsh[t] = zbacc[b * 256 + t] * (0.8f / (float)NNODE);
    __syncthreads();

    // biasl partials: 256 threads, 16 k each (bp is dedicated -> no race)
    if (t < 256) {
        const int o2 = t & 15, g = t >> 4;
        float p = 0.0f;
        #pragma unroll
        for (int kk = 0; kk < 16; ++kk) {
            int k = 16 * g + kk;
            p = fmaf(zsh[k], kern[(long)k * HO + c0 + o2], p);
        }
        bp[g][o2] = p;
    }

    // gather: 2 x uint4 (8 bf16 each) per sorted row; column-major scatter
    if (t < NNODE * 2) {
        int j = t >> 1, q = (t & 1) * 8;
        int m = perms[j];
        u16x8 raw = *(const u16x8*)(xp + ((long)b * NNODE + m) * HO + c0 + q);
        #pragma unroll
        for (int oo = 0; oo < 8; ++oo) Vs[(q + oo) * NP + j] = bf2f(raw[oo]);
    }
    __syncthreads();

    if (t < 16) {
        float s = bias[c0 + t];
        #pragma unroll
        for (int g = 0; g < 16; ++g) s += bp[g][t];
        biasl[t] = s;       // consumed at emit; barriers in between
    }

    const int c = t >> 4, o = t & 15;   // 64 chunks x 16 cols

    // S1: w1-weighted suffix sums within chunk
    {
        float acc = 0.0f;
        #pragma unroll
        for (int jj = CHN - 1; jj >= 0; --jj) {
            int j = c * CHN + jj;
            if (j < NNODE) {
                acc = fmaf(w1s[j], Vs[o * NP + j], acc);
                S1[o * NP + j] = acc;
            }
        }
        CT[c][o] = acc;
    }
    __syncthreads();
    // wave-parallel suffix scan of CT: wave w scans column w over 64 chunks
    {
        const int w = t >> 6, ln = t & 63;
        float v = CT[ln][w];
        #pragma unroll
        for (int s = 1; s < 64; s <<= 1) {
            float tmp = __shfl_down(v, s, 64);
            if (ln + s < 64) v += tmp;
        }
        CT[ln][w] = v;
    }
    __syncthreads();
    {
        float off = (c < 63) ? CT[c + 1][o] : 0.0f;
        #pragma unroll
        for (int jj = 0; jj < CHN; ++jj) {
            int j = c * CHN + jj;
            if (j < NNODE) S1[o * NP + j] += off;
        }
        if (c == 0) S1[o * NP + NNODE] = 0.0f;
    }
    // S2: w2-weighted exclusive prefix within chunk, in place over Vs
    {
        float acc = 0.0f;
        #pragma unroll
        for (int jj = 0; jj < CHN; ++jj) {
            int j = c * CHN + jj;
            if (j < NNODE) {
                float tmp = Vs[o * NP + j];
                Vs[o * NP + j] = acc;
                acc = fmaf(w2s[j], tmp, acc);
            }
        }
        CT2[c][o] = acc;
    }
    __syncthreads();
    // wave-parallel prefix scan of CT2: wave w scans column w over 64 chunks
    {
        const int w = t >> 6, ln = t & 63;
        float v = CT2[ln][w];
        #pragma unroll
        for (int s = 1; s < 64; s <<= 1) {
            float tmp = __shfl_up(v, s, 64);
            if (ln >= s) v += tmp;
        }
        CT2[ln][w] = v;
    }
    __syncthreads();
    {
        float off = (c > 0) ? CT2[c - 1][o] : 0.0f;
        #pragma unroll
        for (int jj = 0; jj < CHN; ++jj) {
            int j = c * CHN + jj;
            if (j < NNODE) Vs[o * NP + j] += off;
        }
        if (c == 63) Vs[o * NP + NNODE] = CT2[63][o];
    }
    __syncthreads();

    // emit: float4 per (row, col-quad)
    for (int idx = t; idx < NNODE * 4; idx += 1024) {
        int n = idx >> 2, q = (idx & 3) * 4;
        int tt = tls[n];
        float g1 = g1s[n], g2 = g2s[n];
        float r[4];
        #pragma unroll
        for (int rr = 0; rr < 4; ++rr) {
            int oo = q + rr;
            float v = g1 * S1[oo * NP + tt] + g2 * Vs[oo * NP + tt] + biasl[oo];
            r[rr] = (v > 0.0f) ? v : (__expf(v) - 1.0f);
        }
        *(float4*)(out + ((long)b * NNODE + n) * HO + c0 + q) =
            make_float4(r[0], r[1], r[2], r[3]);
    }
}

extern "C" void kernel_launch(void* const* d_in, const int* in_sizes, int n_in,
                              void* d_out, int out_size, void* d_ws, size_t ws_size,
                              hipStream_t stream) {
    const float* x     = (const float*)d_in[0];   // [108,392,256]
    const float* w_mlp = (const float*)d_in[2];   // [256,256]
    const float* b_mlp = (const float*)d_in[3];   // [256]
    const float* kern  = (const float*)d_in[4];   // [256,4,64] == [256,256]
    const float* ask   = (const float*)d_in[5];   // [64,4,1]
    const float* ank   = (const float*)d_in[6];   // [64,4,1]
    const float* bias  = (const float*)d_in[7];   // [256]
    float* out = (float*)d_out;

    const long TENS = (long)MROWS * IDIM;         // 10,838,016
    float*  s0    = (float*)d_ws;                 // [B,H,N]
    float*  ng0   = s0 + SGH;
    float*  zbacc = ng0 + SGH;                    // [B,256] atomically built
    float2* w12G  = (float2*)(zbacc + (long)BATCH * IDIM);
    float2* g12G  = w12G + SGH;
    uint*   ptG   = (uint*)(g12G + SGH);
    ushort* xp_bf = (ushort*)(ptG + SGH);         // [B,N,H*O] bf16 (xp0)
    ushort* wshuf = xp_bf + TENS;                 // [65536] frag-order w_mlp
    ushort* kshuf = wshuf + 65536;                // [65536] frag-order kernel

    dim3 blk(256);

    // 0) weight shuffle + zbacc zeroing (fused)
    wcvt<<<dim3(512), blk, 0, stream>>>(w_mlp, kern, wshuf, kshuf, zbacc);

    // 1) fused: mlp(sigmoid, LDS-only) -> col-sums -> xp0 + s0/ng0
    fused_gemm<<<dim3(13, BATCH), dim3(256), 0, stream>>>(
        x, wshuf, kshuf, b_mlp, zbacc, xp_bf, ask, ank, s0, ng0);

    // 2) attention stats: fused sb/ngb + shfl sort + wave-shfl D1/D2 scans
    attn_stats<<<dim3(BATCH * HEADS), dim3(512), 0, stream>>>(
        s0, ng0, zbacc, kern, ask, ank, ptG, w12G, g12G);

    // 3) attention scan: fused biasl + wave-parallel cross-chunk scans + emit
    attn_scan<<<dim3(4, BATCH * HEADS), dim3(1024), 0, stream>>>(
        xp_bf, ptG, w12G, g12G, zbacc, kern, bias, out);
}